// Round 5
// baseline (11726.988 us; speedup 1.0000x reference)
//
#include <hip/hip_runtime.h>
#include <math.h>

// ---------------------------------------------------------------------------
// TinyMyo 8ch/400tok quant transformer — bf16-MFMA v4.
// v3 race fixed: residual-add moved into GEMM pass-2 epilogue (OM=3);
// LayerNorm reads only H (no read of the aliased A region).
// ---------------------------------------------------------------------------

typedef unsigned int u32;
typedef unsigned short u16;
typedef __attribute__((ext_vector_type(8))) short short8;
typedef __attribute__((ext_vector_type(4))) float f32x4;

#define MFMA16(a, b, c) __builtin_amdgcn_mfma_f32_16x16x32_bf16((a), (b), (c), 0, 0, 0)

constexpr int NL = 8;
constexpr long ROWS = 102400;  // B*SEQ

// ---- scale slots (each 16 shadow u32 words) ----
constexpr int SLOT_X = 0, SLOT_PW = 1, SLOT_EMB = 2, SLOT_CLF = 3, SLOT_POOL = 4;
// per-layer base 16+i*16: +0 wqkv +1 wo +2 w1 +3 w2 +4 q +5 k +6 v
//  +7 scores +8 probmax +9 ctx +10 attnout +11 gelu +12 mlpout
constexpr int N_SLOT_WORDS = 200 * 16;

// ---- ws layout (float units), total 59,653,536 floats = 238.6 MB ----
constexpr long OFF_GM = 3200;               // 307200 (also W-code scratch wo/w1/w2)
constexpr long OFF_GL = OFF_GM + 307200;    // 307200
constexpr long OFF_POOL = OFF_GL + 307200;  // 49152 (also wqkv-code scratch)
constexpr long OFF_PWQ = OFF_POOL + 49152;  // 3840
constexpr long OFF_CLFQ = OFF_PWQ + 3840;   // 1344
constexpr long OFF_H = OFF_CLFQ + 1344;     // 19660800 fp32 residual
constexpr long OFF_A = OFF_H + 19660800;    // 19660800: hi/lo bf16 planes | ctx fp32
constexpr long OFF_U = OFF_A + 19660800;    // 19660800: int8 codes qkv/ctx/gelu

// ---------------------------------------------------------------------------
// helpers
// ---------------------------------------------------------------------------
__device__ __forceinline__ float warpMax(float v) {
#pragma unroll
  for (int o = 32; o > 0; o >>= 1) v = fmaxf(v, __shfl_down(v, o));
  return v;
}

__device__ __forceinline__ float read_max16(const u32* sc, int slot) {
  const u32* p = sc + slot * 16;
  u32 m = 0;
#pragma unroll
  for (int i = 0; i < 16; ++i) m = max(m, p[i]);
  return __uint_as_float(m);
}

__device__ __forceinline__ float fqs(float x, float s) {
  return fminf(fmaxf(rintf(x / s), -128.0f), 127.0f) * s;
}

__device__ __forceinline__ float bf2f(u16 h) { return __uint_as_float(((u32)h) << 16); }
__device__ __forceinline__ u16 f2bf(float f) {  // RNE float->bf16
  u32 b = __float_as_uint(f);
  return (u16)((b + 0x7FFFu + ((b >> 16) & 1u)) >> 16);
}
// exact for integer-valued floats |v| <= 256
__device__ __forceinline__ short i2bf(float v) { return (short)(u16)(__float_as_uint(v) >> 16); }
// 8 int8 codes (two packed words) -> short8 of bf16 codes
__device__ __forceinline__ short8 dec8(int lo, int hi) {
  short8 o;
#pragma unroll
  for (int j = 0; j < 4; ++j) {
    o[j] = i2bf((float)((signed char)(lo >> (8 * j))));
    o[j + 4] = i2bf((float)((signed char)(hi >> (8 * j))));
  }
  return o;
}

// ---------------------------------------------------------------------------
// small utility kernels
// ---------------------------------------------------------------------------
__global__ void k_zero(u32* p, int n) {
  int i = blockIdx.x * blockDim.x + threadIdx.x;
  if (i < n) p[i] = 0u;
}

__global__ __launch_bounds__(256) void k_absmax(const float4* __restrict__ x, long n4,
                                                u32* __restrict__ slot) {
  float m = 0.f;
  for (long i = (long)blockIdx.x * blockDim.x + threadIdx.x; i < n4;
       i += (long)gridDim.x * blockDim.x) {
    float4 v = x[i];
    m = fmaxf(m, fmaxf(fmaxf(fabsf(v.x), fabsf(v.y)), fmaxf(fabsf(v.z), fabsf(v.w))));
  }
  __shared__ float red[4];
  m = warpMax(m);
  int lane = threadIdx.x & 63, w = threadIdx.x >> 6;
  if (lane == 0) red[w] = m;
  __syncthreads();
  if (threadIdx.x == 0) {
    float r = fmaxf(fmaxf(red[0], red[1]), fmaxf(red[2], red[3]));
    atomicMax(slot + (blockIdx.x & 15), __float_as_uint(r));
  }
}

__global__ __launch_bounds__(256) void k_quant4(const float4* __restrict__ in,
                                                float4* __restrict__ out, long n4,
                                                const u32* __restrict__ sc, int slot) {
  float s = read_max16(sc, slot) / 127.0f + 1e-8f;
  for (long i = (long)blockIdx.x * blockDim.x + threadIdx.x; i < n4;
       i += (long)gridDim.x * blockDim.x) {
    float4 v = in[i];
    v.x = fqs(v.x, s); v.y = fqs(v.y, s); v.z = fqs(v.z, s); v.w = fqs(v.w, s);
    out[i] = v;
  }
}

// fp32 -> int8 codes (packed u32)
__global__ __launch_bounds__(256) void k_quant_codes(const float4* __restrict__ in,
                                                     u32* __restrict__ out, long n4,
                                                     const u32* __restrict__ sc, int slot) {
  float s = read_max16(sc, slot) / 127.0f + 1e-8f;
  for (long i = (long)blockIdx.x * blockDim.x + threadIdx.x; i < n4;
       i += (long)gridDim.x * blockDim.x) {
    float4 v = in[i];
    int c0 = (int)fminf(fmaxf(rintf(v.x / s), -128.f), 127.f);
    int c1 = (int)fminf(fmaxf(rintf(v.y / s), -128.f), 127.f);
    int c2 = (int)fminf(fmaxf(rintf(v.z / s), -128.f), 127.f);
    int c3 = (int)fminf(fmaxf(rintf(v.w / s), -128.f), 127.f);
    out[i] = (u32)(c0 & 0xff) | ((u32)(c1 & 0xff) << 8) | ((u32)(c2 & 0xff) << 16) |
             ((u32)(c3 & 0xff) << 24);
  }
}

// ---------------------------------------------------------------------------
// patch embed: 8 rows/block, 192 threads
// ---------------------------------------------------------------------------
__global__ __launch_bounds__(192) void k_patch(const float* __restrict__ x,
                                               const float* __restrict__ pwq,
                                               const float* __restrict__ pb,
                                               const u32* __restrict__ sc,
                                               float* __restrict__ emb,
                                               u32* __restrict__ embSlot) {
  __shared__ float xq[8][20];
  __shared__ float red[3];
  const int tid = threadIdx.x;
  const long rowBase = (long)blockIdx.x * 8;
  const float sx = read_max16(sc, SLOT_X) / 127.0f + 1e-8f;
  if (tid < 160) {
    int r = tid / 20, k = tid % 20;
    xq[r][k] = fqs(x[(rowBase + r) * 20 + k], sx);
  }
  __syncthreads();
  float wreg[20];
#pragma unroll
  for (int k = 0; k < 20; ++k) wreg[k] = pwq[tid * 20 + k];
  const float bias = pb[tid];
  float m = 0.f;
  for (int r = 0; r < 8; ++r) {
    float acc = bias;
#pragma unroll
    for (int k = 0; k < 20; ++k) acc += xq[r][k] * wreg[k];
    emb[(rowBase + r) * 192 + tid] = acc;
    m = fmaxf(m, fabsf(acc));
  }
  m = warpMax(m);
  if ((tid & 63) == 0) red[tid >> 6] = m;
  __syncthreads();
  if (tid == 0)
    atomicMax(embSlot + (blockIdx.x & 15),
              __float_as_uint(fmaxf(fmaxf(red[0], red[1]), red[2])));
}

// ---------------------------------------------------------------------------
// LayerNorm (reads only H). HILO -> hi/lo bf16 planes, else fp32.
// ---------------------------------------------------------------------------
template <bool HILO>
__global__ __launch_bounds__(256) void k_ln(const float* __restrict__ x,
                                            const float* __restrict__ g,
                                            const float* __restrict__ bta,
                                            u16* __restrict__ yh, u16* __restrict__ yl,
                                            float* __restrict__ yf, int rows) {
  int w = threadIdx.x >> 6, lane = threadIdx.x & 63;
  long row = (long)blockIdx.x * 4 + w;
  if (row >= rows) return;
  const float* xr = x + row * 192;
  float v0 = xr[lane], v1 = xr[lane + 64], v2 = xr[lane + 128];
  float s = v0 + v1 + v2;
#pragma unroll
  for (int o = 32; o > 0; o >>= 1) s += __shfl_down(s, o);
  s = __shfl(s, 0);
  float mean = s / 192.0f;
  float d0 = v0 - mean, d1 = v1 - mean, d2 = v2 - mean;
  float q = d0 * d0 + d1 * d1 + d2 * d2;
#pragma unroll
  for (int o = 32; o > 0; o >>= 1) q += __shfl_down(q, o);
  q = __shfl(q, 0);
  float rs = 1.0f / sqrtf(q / 192.0f + 1e-5f);
  float o0 = d0 * rs * g[lane] + bta[lane];
  float o1 = d1 * rs * g[lane + 64] + bta[lane + 64];
  float o2 = d2 * rs * g[lane + 128] + bta[lane + 128];
  if (HILO) {
    long b = row * 192;
    u16 h0 = f2bf(o0), h1 = f2bf(o1), h2 = f2bf(o2);
    yh[b + lane] = h0;       yl[b + lane] = f2bf(o0 - bf2f(h0));
    yh[b + lane + 64] = h1;  yl[b + lane + 64] = f2bf(o1 - bf2f(h1));
    yh[b + lane + 128] = h2; yl[b + lane + 128] = f2bf(o2 - bf2f(h2));
  } else {
    float* yr = yf + row * 192;
    yr[lane] = o0; yr[lane + 64] = o1; yr[lane + 128] = o2;
  }
}

// ---------------------------------------------------------------------------
// weight fp32 -> int8 codes
// ---------------------------------------------------------------------------
__global__ __launch_bounds__(256) void k_wquant(const float4* __restrict__ w,
                                                u32* __restrict__ out, int n4,
                                                const u32* __restrict__ sc, int slot) {
  int i = blockIdx.x * blockDim.x + threadIdx.x;
  if (i >= n4) return;
  float s = read_max16(sc, slot) / 127.0f + 1e-8f;
  float4 v = w[i];
  int c0 = (int)fminf(fmaxf(rintf(v.x / s), -128.f), 127.f);
  int c1 = (int)fminf(fmaxf(rintf(v.y / s), -128.f), 127.f);
  int c2 = (int)fminf(fmaxf(rintf(v.z / s), -128.f), 127.f);
  int c3 = (int)fminf(fmaxf(rintf(v.w / s), -128.f), 127.f);
  out[i] = (u32)(c0 & 0xff) | ((u32)(c1 & 0xff) << 8) | ((u32)(c2 & 0xff) << 16) |
           ((u32)(c3 & 0xff) << 24);
}

// ---------------------------------------------------------------------------
// MFMA GEMM: C[M,N] = op(A)[M,K] · codes(W8[N,K])^T * alpha + bias
// AMODE 0: A = hi/lo bf16 planes; 1: A = int8 codes (alpha *= sA)
// OM 0: fp32 store + absmax; 1: absmax only; 2: int8 code store;
// OM 3: residual add  C += fq(val, sO)   (C = H, fp32)
// BM=128 BN=64 BK=32, 256 thr / 4 waves (2Mx2N), wave = 4x2 16x16 frags
// ---------------------------------------------------------------------------
template <int AMODE, bool GELU, int OM>
__global__ __launch_bounds__(256) void k_gemm(
    const u16* __restrict__ Ahi, const u16* __restrict__ Alo,
    const signed char* __restrict__ A8, int slotA, const signed char* __restrict__ W8,
    int slotW, const float* __restrict__ bias, float* __restrict__ C,
    signed char* __restrict__ C8, int N, int K, u32* __restrict__ sc, int slotO,
    int colsPerSlot) {
  __shared__ __align__(16) u16 Ash[128 * 40];
  __shared__ __align__(16) u16 Asl[128 * 40];
  __shared__ __align__(16) u16 Bsh[64 * 40];
  __shared__ float red[4];
  const int tid = threadIdx.x;
  const long rowBase = (long)blockIdx.y * 128;
  const int colBase = blockIdx.x * 64;
  const float sW = read_max16(sc, slotW) / 127.0f + 1e-8f;
  float alpha = sW;
  if (AMODE == 1) alpha *= read_max16(sc, slotA) / 127.0f + 1e-8f;

  const int lane = tid & 63, wv = tid >> 6;
  const int wm = wv >> 1, wn = wv & 1;
  const int fr = lane & 15, fk = lane >> 4;

  f32x4 acc[4][2];
#pragma unroll
  for (int m = 0; m < 4; ++m)
#pragma unroll
    for (int n = 0; n < 2; ++n) acc[m][n] = (f32x4){0.f, 0.f, 0.f, 0.f};

  const int arow = tid >> 1, ac2 = tid & 1;
  const int bn = tid >> 2, bc = tid & 3;

  for (int k0 = 0; k0 < K; k0 += 32) {
    if (AMODE == 0) {
      const long g = (rowBase + arow) * (long)K + k0 + ac2 * 16;
      *(short8*)&Ash[arow * 40 + ac2 * 16] = *(const short8*)(Ahi + g);
      *(short8*)&Ash[arow * 40 + ac2 * 16 + 8] = *(const short8*)(Ahi + g + 8);
      *(short8*)&Asl[arow * 40 + ac2 * 16] = *(const short8*)(Alo + g);
      *(short8*)&Asl[arow * 40 + ac2 * 16 + 8] = *(const short8*)(Alo + g + 8);
    } else {
      int4 v = *(const int4*)(A8 + (rowBase + arow) * (long)K + k0 + ac2 * 16);
      *(short8*)&Ash[arow * 40 + ac2 * 16] = dec8(v.x, v.y);
      *(short8*)&Ash[arow * 40 + ac2 * 16 + 8] = dec8(v.z, v.w);
    }
    {
      int2 wvv = *(const int2*)(W8 + (long)(colBase + bn) * K + k0 + bc * 8);
      *(short8*)&Bsh[bn * 40 + bc * 8] = dec8(wvv.x, wvv.y);
    }
    __syncthreads();
    short8 bf0 = *(short8*)&Bsh[(wn * 32 + fr) * 40 + fk * 8];
    short8 bf1 = *(short8*)&Bsh[(wn * 32 + 16 + fr) * 40 + fk * 8];
#pragma unroll
    for (int m = 0; m < 4; ++m) {
      short8 ah = *(short8*)&Ash[(wm * 64 + m * 16 + fr) * 40 + fk * 8];
      acc[m][0] = MFMA16(ah, bf0, acc[m][0]);
      acc[m][1] = MFMA16(ah, bf1, acc[m][1]);
      if (AMODE == 0) {
        short8 al = *(short8*)&Asl[(wm * 64 + m * 16 + fr) * 40 + fk * 8];
        acc[m][0] = MFMA16(al, bf0, acc[m][0]);
        acc[m][1] = MFMA16(al, bf1, acc[m][1]);
      }
    }
    __syncthreads();
  }

  float sO = 1.f;
  if (OM >= 2) sO = read_max16(sc, slotO + colBase / colsPerSlot) / 127.0f + 1e-8f;
  const float inv_sqrt2 = 0.70710678118654752440f;
  float vmax = 0.f;
#pragma unroll
  for (int n = 0; n < 2; ++n) {
    const int col = colBase + wn * 32 + n * 16 + fr;
    const float bb = bias[col];
#pragma unroll
    for (int m = 0; m < 4; ++m) {
#pragma unroll
      for (int r = 0; r < 4; ++r) {
        const long row = rowBase + wm * 64 + m * 16 + fk * 4 + r;
        float val = acc[m][n][r] * alpha + bb;
        if (GELU) val = 0.5f * val * (1.0f + erff(val * inv_sqrt2));
        if (OM == 2) {
          float code = fminf(fmaxf(rintf(val / sO), -128.f), 127.f);
          C8[row * N + col] = (signed char)code;
        } else if (OM == 3) {
          C[row * N + col] += fqs(val, sO);
        } else {
          if (OM == 0) C[row * N + col] = val;
          vmax = fmaxf(vmax, fabsf(val));
        }
      }
    }
  }
  if (OM <= 1) {
    float m = warpMax(vmax);
    if ((tid & 63) == 0) red[tid >> 6] = m;
    __syncthreads();
    if (tid == 0) {
      float r = fmaxf(fmaxf(red[0], red[1]), fmaxf(red[2], red[3]));
      atomicMax(sc + (slotO + colBase / colsPerSlot) * 16 + ((blockIdx.x + blockIdx.y) & 15),
                __float_as_uint(r));
    }
  }
}

// ---------------------------------------------------------------------------
// Attention phase 0: global |score| max. Block = 64 q-rows of one (b,h).
// ---------------------------------------------------------------------------
__global__ __launch_bounds__(256) void k_attn0(const signed char* __restrict__ qkv8,
                                               u32* __restrict__ sc, int slotQ, int slotSc) {
  __shared__ __align__(16) u16 Qs[64 * 72];
  __shared__ __align__(16) u16 Ks[128 * 72];
  __shared__ float red[4];
  const int tid = threadIdx.x;
  const int r0 = blockIdx.x * 64;
  const int bh = blockIdx.y, b = bh / 3, hh = bh % 3;
  const signed char* qb = qkv8 + (long)b * 400 * 576 + hh * 64;
  const signed char* kb = qb + 192;
  const float sQ = read_max16(sc, slotQ) / 127.0f + 1e-8f;
  const float sK = read_max16(sc, slotQ + 1) / 127.0f + 1e-8f;
  const float sSc = sQ * sK * 0.125f;

  {
    int row = tid >> 2, c = tid & 3;
    int4 v = make_int4(0, 0, 0, 0);
    if (r0 + row < 400) v = *(const int4*)(qb + (long)(r0 + row) * 576 + c * 16);
    *(short8*)&Qs[row * 72 + c * 16] = dec8(v.x, v.y);
    *(short8*)&Qs[row * 72 + c * 16 + 8] = dec8(v.z, v.w);
  }
  const int lane = tid & 63, w = tid >> 6, fr = lane & 15, fk = lane >> 4;
  __syncthreads();
  short8 qf0 = *(short8*)&Qs[(16 * w + fr) * 72 + fk * 8];
  short8 qf1 = *(short8*)&Qs[(16 * w + fr) * 72 + 32 + fk * 8];

  float vmax = 0.f;
  for (int c0 = 0; c0 < 400; c0 += 128) {
    __syncthreads();
    {
      int trow = tid >> 1, half = tid & 1;
      int4 v0 = make_int4(0, 0, 0, 0), v1 = v0;
      if (c0 + trow < 400) {
        v0 = *(const int4*)(kb + (long)(c0 + trow) * 576 + half * 32);
        v1 = *(const int4*)(kb + (long)(c0 + trow) * 576 + half * 32 + 16);
      }
      *(short8*)&Ks[trow * 72 + half * 32] = dec8(v0.x, v0.y);
      *(short8*)&Ks[trow * 72 + half * 32 + 8] = dec8(v0.z, v0.w);
      *(short8*)&Ks[trow * 72 + half * 32 + 16] = dec8(v1.x, v1.y);
      *(short8*)&Ks[trow * 72 + half * 32 + 24] = dec8(v1.z, v1.w);
    }
    __syncthreads();
#pragma unroll
    for (int tf = 0; tf < 8; ++tf) {
      short8 kf0 = *(short8*)&Ks[(tf * 16 + fr) * 72 + fk * 8];
      short8 kf1 = *(short8*)&Ks[(tf * 16 + fr) * 72 + 32 + fk * 8];
      f32x4 s = (f32x4){0.f, 0.f, 0.f, 0.f};
      s = MFMA16(qf0, kf0, s);
      s = MFMA16(qf1, kf1, s);
#pragma unroll
      for (int r = 0; r < 4; ++r) vmax = fmaxf(vmax, fabsf(s[r]));
    }
  }
  float m = warpMax(vmax * sSc);
  if (lane == 0) red[w] = m;
  __syncthreads();
  if (tid == 0) {
    float r = fmaxf(fmaxf(red[0], red[1]), fmaxf(red[2], red[3]));
    atomicMax(sc + slotSc * 16 + ((blockIdx.x + blockIdx.y) & 15), __float_as_uint(r));
  }
}

// ---------------------------------------------------------------------------
// Attention phase 1: score codes -> LDS, integer row max, flat exp-sum.
// gm = maxcode*sS, gl = sum(exp), probmax cand = 1/gl.
// ---------------------------------------------------------------------------
__global__ __launch_bounds__(256) void k_attn1(const signed char* __restrict__ qkv8,
                                               float* __restrict__ gm, float* __restrict__ gl,
                                               u32* __restrict__ sc, int slotQ, int slotSc,
                                               int slotPr) {
  __shared__ __align__(16) u16 Qs[64 * 72];
  __shared__ __align__(16) u16 Ks[128 * 72];
  __shared__ __align__(4) signed char P8[400 * 68];
  __shared__ float rowc[64];
  __shared__ float red[4];
  const int tid = threadIdx.x;
  const int r0 = blockIdx.x * 64;
  const int bh = blockIdx.y, b = bh / 3, hh = bh % 3;
  const signed char* qb = qkv8 + (long)b * 400 * 576 + hh * 64;
  const signed char* kb = qb + 192;
  const float sQ = read_max16(sc, slotQ) / 127.0f + 1e-8f;
  const float sK = read_max16(sc, slotQ + 1) / 127.0f + 1e-8f;
  const float sSc = sQ * sK * 0.125f;
  const float sS = read_max16(sc, slotSc) / 127.0f + 1e-8f;

  {
    int row = tid >> 2, c = tid & 3;
    int4 v = make_int4(0, 0, 0, 0);
    if (r0 + row < 400) v = *(const int4*)(qb + (long)(r0 + row) * 576 + c * 16);
    *(short8*)&Qs[row * 72 + c * 16] = dec8(v.x, v.y);
    *(short8*)&Qs[row * 72 + c * 16 + 8] = dec8(v.z, v.w);
  }
  const int lane = tid & 63, w = tid >> 6, fr = lane & 15, fk = lane >> 4;
  __syncthreads();
  short8 qf0 = *(short8*)&Qs[(16 * w + fr) * 72 + fk * 8];
  short8 qf1 = *(short8*)&Qs[(16 * w + fr) * 72 + 32 + fk * 8];

  float cm[4];
#pragma unroll
  for (int r = 0; r < 4; ++r) cm[r] = -1e30f;

  for (int c0 = 0; c0 < 400; c0 += 128) {
    __syncthreads();
    {
      int trow = tid >> 1, half = tid & 1;
      int4 v0 = make_int4(0, 0, 0, 0), v1 = v0;
      if (c0 + trow < 400) {
        v0 = *(const int4*)(kb + (long)(c0 + trow) * 576 + half * 32);
        v1 = *(const int4*)(kb + (long)(c0 + trow) * 576 + half * 32 + 16);
      }
      *(short8*)&Ks[trow * 72 + half * 32] = dec8(v0.x, v0.y);
      *(short8*)&Ks[trow * 72 + half * 32 + 8] = dec8(v0.z, v0.w);
      *(short8*)&Ks[trow * 72 + half * 32 + 16] = dec8(v1.x, v1.y);
      *(short8*)&Ks[trow * 72 + half * 32 + 24] = dec8(v1.z, v1.w);
    }
    __syncthreads();
#pragma unroll
    for (int tf = 0; tf < 8; ++tf) {
      short8 kf0 = *(short8*)&Ks[(tf * 16 + fr) * 72 + fk * 8];
      short8 kf1 = *(short8*)&Ks[(tf * 16 + fr) * 72 + 32 + fk * 8];
      f32x4 s = (f32x4){0.f, 0.f, 0.f, 0.f};
      s = MFMA16(qf0, kf0, s);
      s = MFMA16(qf1, kf1, s);
      const int t = c0 + tf * 16 + fr;
      if (t < 400) {
        int q0 = 16 * w + fk * 4;
        u32 pack = 0;
#pragma unroll
        for (int r = 0; r < 4; ++r) {
          float cf = fminf(fmaxf(rintf((s[r] * sSc) / sS), -128.f), 127.f);
          cm[r] = fmaxf(cm[r], cf);
          pack |= ((u32)((int)cf & 0xff)) << (8 * r);
        }
        *(u32*)&P8[t * 68 + q0] = pack;
      }
    }
  }
  // merge row max over the 16 t-lanes (fr bits)
#pragma unroll
  for (int off = 1; off < 16; off <<= 1) {
#pragma unroll
    for (int r = 0; r < 4; ++r) cm[r] = fmaxf(cm[r], __shfl_xor(cm[r], off));
  }
  if (fr == 0) {
#pragma unroll
    for (int r = 0; r < 4; ++r) rowc[16 * w + fk * 4 + r] = cm[r];
  }
  __syncthreads();

  // flat exp sum: 4 lanes (fk) per row q = 16w + fr
  const int qloc = 16 * w + fr;
  const float rowm = rowc[qloc] * sS;
  float sum = 0.f;
  for (int t = fk; t < 400; t += 4) {
    float c = (float)P8[t * 68 + qloc];
    sum += expf(c * sS - rowm);
  }
  sum += __shfl_xor(sum, 16);
  sum += __shfl_xor(sum, 32);
  float cand = 0.f;
  const int gq = r0 + qloc;
  if (fk == 0 && gq < 400) {
    gm[(long)bh * 400 + gq] = rowm;
    gl[(long)bh * 400 + gq] = sum;
    cand = 1.0f / sum;
  }
  float m = warpMax(cand);
  if (lane == 0) red[w] = m;
  __syncthreads();
  if (tid == 0) {
    float r = fmaxf(fmaxf(red[0], red[1]), fmaxf(red[2], red[3]));
    atomicMax(sc + slotPr * 16 + ((blockIdx.x + blockIdx.y) & 15), __float_as_uint(r));
  }
}

// ---------------------------------------------------------------------------
// Attention phase 2: probs -> uint8 codes -> PV (out^T = Vt · P^T) + absmax.
// ---------------------------------------------------------------------------
__global__ __launch_bounds__(256) void k_attn_pv(const signed char* __restrict__ qkv8,
                                                 float* __restrict__ ctx,
                                                 const float* __restrict__ gm,
                                                 const float* __restrict__ gl,
                                                 u32* __restrict__ sc, int slotQ, int slotSc,
                                                 int slotPr, int slotCtx) {
  __shared__ __align__(16) u16 Qs[64 * 72];
  __shared__ __align__(16) u16 Ks[128 * 72];
  __shared__ __align__(16) u16 Ps[64 * 136];
  __shared__ __align__(16) u16 Vt[64 * 136];
  __shared__ float red[4];
  const int tid = threadIdx.x;
  const int r0 = blockIdx.x * 64;
  const int bh = blockIdx.y, b = bh / 3, hh = bh % 3;
  const signed char* qb = qkv8 + (long)b * 400 * 576 + hh * 64;
  const signed char* kb = qb + 192;
  const signed char* vb = qb + 384;
  const float sQ = read_max16(sc, slotQ) / 127.0f + 1e-8f;
  const float sK = read_max16(sc, slotQ + 1) / 127.0f + 1e-8f;
  const float sV = read_max16(sc, slotQ + 2) / 127.0f + 1e-8f;
  const float sSc = sQ * sK * 0.125f;
  const float sS = read_max16(sc, slotSc) / 127.0f + 1e-8f;
  const float sP = read_max16(sc, slotPr) / 255.0f + 1e-8f;
  const float sPV = sP * sV;

  {
    int row = tid >> 2, c = tid & 3;
    int4 v = make_int4(0, 0, 0, 0);
    if (r0 + row < 400) v = *(const int4*)(qb + (long)(r0 + row) * 576 + c * 16);
    *(short8*)&Qs[row * 72 + c * 16] = dec8(v.x, v.y);
    *(short8*)&Qs[row * 72 + c * 16 + 8] = dec8(v.z, v.w);
  }
  const int lane = tid & 63, w = tid >> 6, fr = lane & 15, fk = lane >> 4;
  __syncthreads();
  short8 qf0 = *(short8*)&Qs[(16 * w + fr) * 72 + fk * 8];
  short8 qf1 = *(short8*)&Qs[(16 * w + fr) * 72 + 32 + fk * 8];

  float rowm[4], rowl[4];
#pragma unroll
  for (int r = 0; r < 4; ++r) {
    int q = r0 + 16 * w + fk * 4 + r;
    if (q > 399) q = 399;
    rowm[r] = gm[(long)bh * 400 + q];
    rowl[r] = gl[(long)bh * 400 + q];
  }
  f32x4 accT[4];
#pragma unroll
  for (int qf = 0; qf < 4; ++qf) accT[qf] = (f32x4){0.f, 0.f, 0.f, 0.f};

  const int vtp = tid & 63;  // t-pair index for V staging

  for (int c0 = 0; c0 < 400; c0 += 128) {
    __syncthreads();
    {  // K chunk (bf16 codes, row-major)
      int trow = tid >> 1, half = tid & 1;
      int4 v0 = make_int4(0, 0, 0, 0), v1 = v0;
      if (c0 + trow < 400) {
        const signed char* kr = kb + (long)(c0 + trow) * 576 + half * 32;
        v0 = *(const int4*)kr;
        v1 = *(const int4*)(kr + 16);
      }
      *(short8*)&Ks[trow * 72 + half * 32] = dec8(v0.x, v0.y);
      *(short8*)&Ks[trow * 72 + half * 32 + 8] = dec8(v0.z, v0.w);
      *(short8*)&Ks[trow * 72 + half * 32 + 16] = dec8(v1.x, v1.y);
      *(short8*)&Ks[trow * 72 + half * 32 + 24] = dec8(v1.z, v1.w);
    }
    {  // V chunk transposed: thread handles rows (2vtp,2vtp+1), d in [16w,16w+16)
      int4 u0 = make_int4(0, 0, 0, 0), u1 = u0;
      int t0 = c0 + 2 * vtp;
      if (t0 < 400) u0 = *(const int4*)(vb + (long)t0 * 576 + w * 16);
      if (t0 + 1 < 400) u1 = *(const int4*)(vb + (long)(t0 + 1) * 576 + w * 16);
      const signed char* p0 = (const signed char*)&u0;
      const signed char* p1 = (const signed char*)&u1;
#pragma unroll
      for (int j = 0; j < 16; ++j) {
        u32 val = (u32)(u16)i2bf((float)p0[j]) | (((u32)(u16)i2bf((float)p1[j])) << 16);
        *(u32*)&Vt[(w * 16 + j) * 136 + 2 * vtp] = val;
      }
    }
    __syncthreads();
    // scores -> prob codes into Ps[q][t]
#pragma unroll
    for (int tf = 0; tf < 8; ++tf) {
      short8 kf0 = *(short8*)&Ks[(tf * 16 + fr) * 72 + fk * 8];
      short8 kf1 = *(short8*)&Ks[(tf * 16 + fr) * 72 + 32 + fk * 8];
      f32x4 s = (f32x4){0.f, 0.f, 0.f, 0.f};
      s = MFMA16(qf0, kf0, s);
      s = MFMA16(qf1, kf1, s);
      const int t = c0 + tf * 16 + fr;
#pragma unroll
      for (int r = 0; r < 4; ++r) {
        const int q = r0 + 16 * w + fk * 4 + r;
        float pu = 0.f;
        if (q < 400 && t < 400) {
          float qv = fqs(s[r] * sSc, sS);
          float p = expf(qv - rowm[r]) / rowl[r];
          pu = fminf(fmaxf(rintf(p / sP), 0.f), 255.f);
        }
        Ps[(16 * w + fk * 4 + r) * 136 + tf * 16 + fr] = (u16)i2bf(pu);
      }
    }
    __syncthreads();
    // PV: accT[qf] += Vt-frag · P^T-frag
    short8 vf0 = *(short8*)&Vt[(16 * w + fr) * 136 + 0 + fk * 8];
    short8 vf1 = *(short8*)&Vt[(16 * w + fr) * 136 + 32 + fk * 8];
    short8 vf2 = *(short8*)&Vt[(16 * w + fr) * 136 + 64 + fk * 8];
    short8 vf3 = *(short8*)&Vt[(16 * w + fr) * 136 + 96 + fk * 8];
#pragma unroll
    for (int qf = 0; qf < 4; ++qf) {
      short8 pf0 = *(short8*)&Ps[(qf * 16 + fr) * 136 + 0 + fk * 8];
      short8 pf1 = *(short8*)&Ps[(qf * 16 + fr) * 136 + 32 + fk * 8];
      short8 pf2 = *(short8*)&Ps[(qf * 16 + fr) * 136 + 64 + fk * 8];
      short8 pf3 = *(short8*)&Ps[(qf * 16 + fr) * 136 + 96 + fk * 8];
      accT[qf] = MFMA16(vf0, pf0, accT[qf]);
      accT[qf] = MFMA16(vf1, pf1, accT[qf]);
      accT[qf] = MFMA16(vf2, pf2, accT[qf]);
      accT[qf] = MFMA16(vf3, pf3, accT[qf]);
    }
  }
  float vmax = 0.f;
#pragma unroll
  for (int qf = 0; qf < 4; ++qf) {
    const int q = r0 + qf * 16 + fr;
    if (q < 400) {
      float4 o;
      o.x = accT[qf][0] * sPV; o.y = accT[qf][1] * sPV;
      o.z = accT[qf][2] * sPV; o.w = accT[qf][3] * sPV;
      vmax = fmaxf(vmax, fmaxf(fmaxf(fabsf(o.x), fabsf(o.y)), fmaxf(fabsf(o.z), fabsf(o.w))));
      *(float4*)&ctx[(long)(b * 400 + q) * 192 + hh * 64 + 16 * w + fk * 4] = o;
    }
  }
  float m = warpMax(vmax);
  if (lane == 0) red[w] = m;
  __syncthreads();
  if (tid == 0) {
    float r = fmaxf(fmaxf(red[0], red[1]), fmaxf(red[2], red[3]));
    atomicMax(sc + slotCtx * 16 + ((blockIdx.x + blockIdx.y) & 15), __float_as_uint(r));
  }
}

// ---------------------------------------------------------------------------
// final pool + logits
// ---------------------------------------------------------------------------
__global__ __launch_bounds__(192) void k_pool(const float* __restrict__ xln,
                                              float* __restrict__ pooled,
                                              u32* __restrict__ slot) {
  int b = blockIdx.x, d = threadIdx.x;
  float sum = 0.f;
  for (int s = 0; s < 400; ++s) sum += xln[((long)b * 400 + s) * 192 + d];
  float v = sum / 400.0f;
  pooled[(long)b * 192 + d] = v;
  __shared__ float red[3];
  float m = warpMax(fabsf(v));
  if ((d & 63) == 0) red[d >> 6] = m;
  __syncthreads();
  if (d == 0)
    atomicMax(slot + (b & 15), __float_as_uint(fmaxf(fmaxf(red[0], red[1]), red[2])));
}

__global__ __launch_bounds__(64) void k_logits(const float* __restrict__ pooled,
                                               const float* __restrict__ clfq,
                                               const float* __restrict__ clfb,
                                               const u32* __restrict__ sc,
                                               float* __restrict__ out) {
  int c = blockIdx.x, b = blockIdx.y, lane = threadIdx.x;
  float sp = read_max16(sc, SLOT_POOL) / 127.0f + 1e-8f;
  float acc = 0.f;
#pragma unroll
  for (int j = 0; j < 3; ++j) {
    int d = lane + 64 * j;
    acc += fqs(pooled[(long)b * 192 + d], sp) * clfq[c * 192 + d];
  }
#pragma unroll
  for (int o = 32; o > 0; o >>= 1) acc += __shfl_down(acc, o);
  if (lane == 0) out[b * 7 + c] = acc + clfb[c];
}

// ---------------------------------------------------------------------------
// host
// ---------------------------------------------------------------------------
static inline int gsz(long n4, long cap) {
  long g = (n4 + 255) / 256;
  return (int)(g < cap ? g : cap);
}

extern "C" void kernel_launch(void* const* d_in, const int* in_sizes, int n_in,
                              void* d_out, int out_size, void* d_ws, size_t ws_size,
                              hipStream_t stream) {
  (void)in_sizes; (void)n_in; (void)out_size; (void)ws_size;

  const float* x = (const float*)d_in[0];
  const float* pw = (const float*)d_in[1];
  const float* pb = (const float*)d_in[2];
  const float* ln1g = (const float*)d_in[3];
  const float* ln1b = (const float*)d_in[4];
  const float* wqkv = (const float*)d_in[5];
  const float* bqkv = (const float*)d_in[6];
  const float* wo = (const float*)d_in[7];
  const float* bo = (const float*)d_in[8];
  const float* ln2g = (const float*)d_in[9];
  const float* ln2b = (const float*)d_in[10];
  const float* w1 = (const float*)d_in[11];
  const float* b1 = (const float*)d_in[12];
  const float* w2 = (const float*)d_in[13];
  const float* b2 = (const float*)d_in[14];
  const float* lnfg = (const float*)d_in[15];
  const float* lnfb = (const float*)d_in[16];
  const float* clfw = (const float*)d_in[17];
  const float* clfb = (const float*)d_in[18];

  float* ws = (float*)d_ws;
  u32* sc = (u32*)d_ws;
  float* GM = ws + OFF_GM;
  float* GL = ws + OFF_GL;
  float* POOL = ws + OFF_POOL;
  float* PWQ = ws + OFF_PWQ;
  float* CLFQ = ws + OFF_CLFQ;
  float* H = ws + OFF_H;
  float* Af = ws + OFF_A;                     // fp32 view of A region (ctx / final LN)
  u16* XH = (u16*)(ws + OFF_A);               // hi plane
  u16* XL = XH + 19660800;                    // lo plane
  signed char* U8 = (signed char*)(ws + OFF_U);
  // weight-code scratch (regions idle at those times)
  signed char* WQC = (signed char*)POOL;      // 110592 B in POOL region
  signed char* WOC = (signed char*)GM;        // 36864 B
  signed char* W1C = WOC + 36864;             // 147456 B
  signed char* W2C = W1C + 147456;            // 147456 B (all within GM region)
  float* out = (float*)d_out;

  k_zero<<<(N_SLOT_WORDS + 255) / 256, 256, 0, stream>>>(sc, N_SLOT_WORDS);

  auto amax = [&](const float* p, long n, int slot) {
    k_absmax<<<gsz(n / 4, 256), 256, 0, stream>>>((const float4*)p, n / 4, sc + slot * 16);
  };
  amax(pw, 3840, SLOT_PW);
  amax(clfw, 1344, SLOT_CLF);
  amax(x, 2048000, SLOT_X);
  for (int i = 0; i < NL; ++i) {
    int Lb = 16 + i * 16;
    amax(wqkv + (long)i * 110592, 110592, Lb + 0);
    amax(wo + (long)i * 36864, 36864, Lb + 1);
    amax(w1 + (long)i * 147456, 147456, Lb + 2);
    amax(w2 + (long)i * 147456, 147456, Lb + 3);
  }
  k_quant4<<<gsz(960, 256), 256, 0, stream>>>((const float4*)pw, (float4*)PWQ, 960, sc, SLOT_PW);
  k_quant4<<<gsz(336, 256), 256, 0, stream>>>((const float4*)clfw, (float4*)CLFQ, 336, sc,
                                              SLOT_CLF);

  // patch embed -> Af -> quant into H; first LN -> planes
  k_patch<<<12800, 192, 0, stream>>>(x, PWQ, pb, sc, Af, sc + SLOT_EMB * 16);
  k_quant4<<<2048, 256, 0, stream>>>((const float4*)Af, (float4*)H, 19660800 / 4, sc, SLOT_EMB);
  k_ln<true><<<(int)(ROWS / 4), 256, 0, stream>>>(H, ln1g, ln1b, XH, XL, nullptr, (int)ROWS);

  for (int i = 0; i < NL; ++i) {
    int Lb = 16 + i * 16;
    // --- attention ---
    k_wquant<<<108, 256, 0, stream>>>((const float4*)(wqkv + (long)i * 110592), (u32*)WQC,
                                      27648, sc, Lb + 0);
    {
      dim3 g(9, 800);
      k_gemm<0, false, 1><<<g, 256, 0, stream>>>(XH, XL, nullptr, 0, WQC, Lb + 0,
                                                 bqkv + i * 576, nullptr, nullptr, 576, 192, sc,
                                                 Lb + 4, 192);
      k_gemm<0, false, 2><<<g, 256, 0, stream>>>(XH, XL, nullptr, 0, WQC, Lb + 0,
                                                 bqkv + i * 576, nullptr, U8, 576, 192, sc,
                                                 Lb + 4, 192);
    }
    {
      dim3 ga(7, 768);
      k_attn0<<<ga, 256, 0, stream>>>(U8, sc, Lb + 4, Lb + 7);
      k_attn1<<<ga, 256, 0, stream>>>(U8, GM, GL, sc, Lb + 4, Lb + 7, Lb + 8);
      k_attn_pv<<<ga, 256, 0, stream>>>(U8, Af, GM, GL, sc, Lb + 4, Lb + 7, Lb + 8, Lb + 9);
    }
    // ctx fp32 (Af) -> int8 codes (U8); quantize wo/w1/w2 codes (GM idle now)
    k_quant_codes<<<2048, 256, 0, stream>>>((const float4*)Af, (u32*)U8, 19660800 / 4, sc,
                                            Lb + 9);
    k_wquant<<<36, 256, 0, stream>>>((const float4*)(wo + (long)i * 36864), (u32*)WOC, 9216,
                                     sc, Lb + 1);
    k_wquant<<<144, 256, 0, stream>>>((const float4*)(w1 + (long)i * 147456), (u32*)W1C, 36864,
                                      sc, Lb + 2);
    k_wquant<<<144, 256, 0, stream>>>((const float4*)(w2 + (long)i * 147456), (u32*)W2C, 36864,
                                      sc, Lb + 3);
    {
      dim3 g(3, 800);
      // pass 1: attn-out absmax; pass 2: H += fq(attn_out)
      k_gemm<1, false, 1><<<g, 256, 0, stream>>>(nullptr, nullptr, U8, Lb + 9, WOC, Lb + 1,
                                                 bo + i * 192, nullptr, nullptr, 192, 192, sc,
                                                 Lb + 10, 192);
      k_gemm<1, false, 3><<<g, 256, 0, stream>>>(nullptr, nullptr, U8, Lb + 9, WOC, Lb + 1,
                                                 bo + i * 192, H, nullptr, 192, 192, sc,
                                                 Lb + 10, 192);
    }
    // LN2 (reads only H) -> planes
    k_ln<true><<<(int)(ROWS / 4), 256, 0, stream>>>(H, ln2g + i * 192, ln2b + i * 192, XH, XL,
                                                    nullptr, (int)ROWS);
    // --- MLP ---
    {
      dim3 g(12, 800);
      k_gemm<0, true, 1><<<g, 256, 0, stream>>>(XH, XL, nullptr, 0, W1C, Lb + 2, b1 + i * 768,
                                                nullptr, nullptr, 768, 192, sc, Lb + 11, 768);
      k_gemm<0, true, 2><<<g, 256, 0, stream>>>(XH, XL, nullptr, 0, W1C, Lb + 2, b1 + i * 768,
                                                nullptr, U8, 768, 192, sc, Lb + 11, 768);
    }
    {
      dim3 g(3, 800);
      // pass 1: mlp-out absmax; pass 2: H += fq(mlp_out)
      k_gemm<1, false, 1><<<g, 256, 0, stream>>>(nullptr, nullptr, U8, Lb + 11, W2C, Lb + 3,
                                                 b2 + i * 192, nullptr, nullptr, 192, 768, sc,
                                                 Lb + 12, 192);
      k_gemm<1, false, 3><<<g, 256, 0, stream>>>(nullptr, nullptr, U8, Lb + 11, W2C, Lb + 3,
                                                 b2 + i * 192, H, nullptr, 192, 768, sc,
                                                 Lb + 12, 192);
    }
    // next LN (ln1 of i+1) or final LN -> fp32 into Af
    if (i < NL - 1) {
      k_ln<true><<<(int)(ROWS / 4), 256, 0, stream>>>(H, ln1g + (i + 1) * 192,
                                                      ln1b + (i + 1) * 192, XH, XL, nullptr,
                                                      (int)ROWS);
    } else {
      k_ln<false><<<(int)(ROWS / 4), 256, 0, stream>>>(H, lnfg, lnfb, nullptr, nullptr, Af,
                                                       (int)ROWS);
    }
  }

  // pool + classifier
  k_pool<<<256, 192, 0, stream>>>(Af, POOL, sc + SLOT_POOL * 16);
  {
    dim3 g(7, 256);
    k_logits<<<g, 64, 0, stream>>>(POOL, CLFQ, clfb, sc, out);
  }
}

// Round 6
// 10237.237 us; speedup vs baseline: 1.1455x; 1.1455x over previous
//
#include <hip/hip_runtime.h>
#include <math.h>

// ---------------------------------------------------------------------------
// TinyMyo 8ch/400tok quant transformer — v5: i8-MFMA attention + GEMMs.
// All quantized tensors are exact integer grids; mfma_i32_*_i8 accumulates
// them exactly (|sums| < 2^24), value-identical to the passing bf16 path.
// ---------------------------------------------------------------------------

typedef unsigned int u32;
typedef unsigned short u16;
typedef __attribute__((ext_vector_type(8))) short short8;
typedef __attribute__((ext_vector_type(4))) float f32x4;
typedef __attribute__((ext_vector_type(4))) int int4v;

#define MFMA16(a, b, c) __builtin_amdgcn_mfma_f32_16x16x32_bf16((a), (b), (c), 0, 0, 0)
#define MFMA_I8(a, b, c) __builtin_amdgcn_mfma_i32_16x16x64_i8((a), (b), (c), 0, 0, 0)

constexpr int NL = 8;
constexpr long ROWS = 102400;  // B*SEQ

// ---- scale slots (each 16 shadow u32 words) ----
constexpr int SLOT_X = 0, SLOT_PW = 1, SLOT_EMB = 2, SLOT_CLF = 3, SLOT_POOL = 4;
// per-layer base 16+i*16: +0 wqkv +1 wo +2 w1 +3 w2 +4 q +5 k +6 v
//  +7 scores +8 probmax +9 ctx +10 attnout +11 gelu +12 mlpout
constexpr int N_SLOT_WORDS = 200 * 16;

// ---- ws layout (float units), total 59,653,536 floats = 238.6 MB ----
constexpr long OFF_GM = 3200;               // 307200 (also wo/w1/w2 code scratch)
constexpr long OFF_GL = OFF_GM + 307200;    // 307200
constexpr long OFF_POOL = OFF_GL + 307200;  // 49152 (wqkv codes / colsumV / pooled)
constexpr long OFF_PWQ = OFF_POOL + 49152;  // 3840
constexpr long OFF_CLFQ = OFF_PWQ + 3840;   // 1344
constexpr long OFF_H = OFF_CLFQ + 1344;     // 19660800 fp32 residual
constexpr long OFF_A = OFF_H + 19660800;    // 19660800: hi/lo planes | ctx fp32
constexpr long OFF_U = OFF_A + 19660800;    // 19660800: codes qkv(59MB)+VT8(19.7MB) / gelu

// ---------------------------------------------------------------------------
// helpers
// ---------------------------------------------------------------------------
__device__ __forceinline__ float warpMax(float v) {
#pragma unroll
  for (int o = 32; o > 0; o >>= 1) v = fmaxf(v, __shfl_down(v, o));
  return v;
}

__device__ __forceinline__ float read_max16(const u32* sc, int slot) {
  const u32* p = sc + slot * 16;
  u32 m = 0;
#pragma unroll
  for (int i = 0; i < 16; ++i) m = max(m, p[i]);
  return __uint_as_float(m);
}

__device__ __forceinline__ float fqs(float x, float s) {
  return fminf(fmaxf(rintf(x / s), -128.0f), 127.0f) * s;
}

__device__ __forceinline__ float bf2f(u16 h) { return __uint_as_float(((u32)h) << 16); }
__device__ __forceinline__ u16 f2bf(float f) {  // RNE float->bf16
  u32 b = __float_as_uint(f);
  return (u16)((b + 0x7FFFu + ((b >> 16) & 1u)) >> 16);
}
// exact for integer-valued floats |v| <= 256
__device__ __forceinline__ short i2bf(float v) { return (short)(u16)(__float_as_uint(v) >> 16); }
// 8 int8 codes (two packed words) -> short8 of bf16 codes
__device__ __forceinline__ short8 dec8(int lo, int hi) {
  short8 o;
#pragma unroll
  for (int j = 0; j < 4; ++j) {
    o[j] = i2bf((float)((signed char)(lo >> (8 * j))));
    o[j + 4] = i2bf((float)((signed char)(hi >> (8 * j))));
  }
  return o;
}

// ---------------------------------------------------------------------------
// small utility kernels
// ---------------------------------------------------------------------------
__global__ void k_zero(u32* p, int n) {
  int i = blockIdx.x * blockDim.x + threadIdx.x;
  if (i < n) p[i] = 0u;
}

__global__ __launch_bounds__(256) void k_absmax(const float4* __restrict__ x, long n4,
                                                u32* __restrict__ slot) {
  float m = 0.f;
  for (long i = (long)blockIdx.x * blockDim.x + threadIdx.x; i < n4;
       i += (long)gridDim.x * blockDim.x) {
    float4 v = x[i];
    m = fmaxf(m, fmaxf(fmaxf(fabsf(v.x), fabsf(v.y)), fmaxf(fabsf(v.z), fabsf(v.w))));
  }
  __shared__ float red[4];
  m = warpMax(m);
  int lane = threadIdx.x & 63, w = threadIdx.x >> 6;
  if (lane == 0) red[w] = m;
  __syncthreads();
  if (threadIdx.x == 0) {
    float r = fmaxf(fmaxf(red[0], red[1]), fmaxf(red[2], red[3]));
    atomicMax(slot + (blockIdx.x & 15), __float_as_uint(r));
  }
}

__global__ __launch_bounds__(256) void k_quant4(const float4* __restrict__ in,
                                                float4* __restrict__ out, long n4,
                                                const u32* __restrict__ sc, int slot) {
  float s = read_max16(sc, slot) / 127.0f + 1e-8f;
  for (long i = (long)blockIdx.x * blockDim.x + threadIdx.x; i < n4;
       i += (long)gridDim.x * blockDim.x) {
    float4 v = in[i];
    v.x = fqs(v.x, s); v.y = fqs(v.y, s); v.z = fqs(v.z, s); v.w = fqs(v.w, s);
    out[i] = v;
  }
}

// fp32 -> int8 codes (packed u32)
__global__ __launch_bounds__(256) void k_quant_codes(const float4* __restrict__ in,
                                                     u32* __restrict__ out, long n4,
                                                     const u32* __restrict__ sc, int slot) {
  float s = read_max16(sc, slot) / 127.0f + 1e-8f;
  for (long i = (long)blockIdx.x * blockDim.x + threadIdx.x; i < n4;
       i += (long)gridDim.x * blockDim.x) {
    float4 v = in[i];
    int c0 = (int)fminf(fmaxf(rintf(v.x / s), -128.f), 127.f);
    int c1 = (int)fminf(fmaxf(rintf(v.y / s), -128.f), 127.f);
    int c2 = (int)fminf(fmaxf(rintf(v.z / s), -128.f), 127.f);
    int c3 = (int)fminf(fmaxf(rintf(v.w / s), -128.f), 127.f);
    out[i] = (u32)(c0 & 0xff) | ((u32)(c1 & 0xff) << 8) | ((u32)(c2 & 0xff) << 16) |
             ((u32)(c3 & 0xff) << 24);
  }
}

// ---------------------------------------------------------------------------
// patch embed: 8 rows/block, 192 threads
// ---------------------------------------------------------------------------
__global__ __launch_bounds__(192) void k_patch(const float* __restrict__ x,
                                               const float* __restrict__ pwq,
                                               const float* __restrict__ pb,
                                               const u32* __restrict__ sc,
                                               float* __restrict__ emb,
                                               u32* __restrict__ embSlot) {
  __shared__ float xq[8][20];
  __shared__ float red[3];
  const int tid = threadIdx.x;
  const long rowBase = (long)blockIdx.x * 8;
  const float sx = read_max16(sc, SLOT_X) / 127.0f + 1e-8f;
  if (tid < 160) {
    int r = tid / 20, k = tid % 20;
    xq[r][k] = fqs(x[(rowBase + r) * 20 + k], sx);
  }
  __syncthreads();
  float wreg[20];
#pragma unroll
  for (int k = 0; k < 20; ++k) wreg[k] = pwq[tid * 20 + k];
  const float bias = pb[tid];
  float m = 0.f;
  for (int r = 0; r < 8; ++r) {
    float acc = bias;
#pragma unroll
    for (int k = 0; k < 20; ++k) acc += xq[r][k] * wreg[k];
    emb[(rowBase + r) * 192 + tid] = acc;
    m = fmaxf(m, fabsf(acc));
  }
  m = warpMax(m);
  if ((tid & 63) == 0) red[tid >> 6] = m;
  __syncthreads();
  if (tid == 0)
    atomicMax(embSlot + (blockIdx.x & 15),
              __float_as_uint(fmaxf(fmaxf(red[0], red[1]), red[2])));
}

// ---------------------------------------------------------------------------
// LayerNorm (reads only H). HILO -> hi/lo bf16 planes, else fp32.
// ---------------------------------------------------------------------------
template <bool HILO>
__global__ __launch_bounds__(256) void k_ln(const float* __restrict__ x,
                                            const float* __restrict__ g,
                                            const float* __restrict__ bta,
                                            u16* __restrict__ yh, u16* __restrict__ yl,
                                            float* __restrict__ yf, int rows) {
  int w = threadIdx.x >> 6, lane = threadIdx.x & 63;
  long row = (long)blockIdx.x * 4 + w;
  if (row >= rows) return;
  const float* xr = x + row * 192;
  float v0 = xr[lane], v1 = xr[lane + 64], v2 = xr[lane + 128];
  float s = v0 + v1 + v2;
#pragma unroll
  for (int o = 32; o > 0; o >>= 1) s += __shfl_down(s, o);
  s = __shfl(s, 0);
  float mean = s / 192.0f;
  float d0 = v0 - mean, d1 = v1 - mean, d2 = v2 - mean;
  float q = d0 * d0 + d1 * d1 + d2 * d2;
#pragma unroll
  for (int o = 32; o > 0; o >>= 1) q += __shfl_down(q, o);
  q = __shfl(q, 0);
  float rs = 1.0f / sqrtf(q / 192.0f + 1e-5f);
  float o0 = d0 * rs * g[lane] + bta[lane];
  float o1 = d1 * rs * g[lane + 64] + bta[lane + 64];
  float o2 = d2 * rs * g[lane + 128] + bta[lane + 128];
  if (HILO) {
    long b = row * 192;
    u16 h0 = f2bf(o0), h1 = f2bf(o1), h2 = f2bf(o2);
    yh[b + lane] = h0;       yl[b + lane] = f2bf(o0 - bf2f(h0));
    yh[b + lane + 64] = h1;  yl[b + lane + 64] = f2bf(o1 - bf2f(h1));
    yh[b + lane + 128] = h2; yl[b + lane + 128] = f2bf(o2 - bf2f(h2));
  } else {
    float* yr = yf + row * 192;
    yr[lane] = o0; yr[lane + 64] = o1; yr[lane + 128] = o2;
  }
}

// ---------------------------------------------------------------------------
// weight fp32 -> int8 codes
// ---------------------------------------------------------------------------
__global__ __launch_bounds__(256) void k_wquant(const float4* __restrict__ w,
                                                u32* __restrict__ out, int n4,
                                                const u32* __restrict__ sc, int slot) {
  int i = blockIdx.x * blockDim.x + threadIdx.x;
  if (i >= n4) return;
  float s = read_max16(sc, slot) / 127.0f + 1e-8f;
  float4 v = w[i];
  int c0 = (int)fminf(fmaxf(rintf(v.x / s), -128.f), 127.f);
  int c1 = (int)fminf(fmaxf(rintf(v.y / s), -128.f), 127.f);
  int c2 = (int)fminf(fmaxf(rintf(v.z / s), -128.f), 127.f);
  int c3 = (int)fminf(fmaxf(rintf(v.w / s), -128.f), 127.f);
  out[i] = (u32)(c0 & 0xff) | ((u32)(c1 & 0xff) << 8) | ((u32)(c2 & 0xff) << 16) |
           ((u32)(c3 & 0xff) << 24);
}

// ---------------------------------------------------------------------------
// bf16-MFMA GEMM (fp32 A via hi/lo planes):
// C = (Ahi+Alo)[M,K] · codes(W8[N,K])^T * sW + bias [,gelu]
// OM 1: absmax only; OM 2: int8 code store. BM=128 BN=192 BK=32.
// 4 waves (2m x 2n); wave = 4m x 6n 16x16 frags.
// ---------------------------------------------------------------------------
template <bool GELU, int OM>
__global__ __launch_bounds__(256) void k_gemmA(
    const u16* __restrict__ Ahi, const u16* __restrict__ Alo,
    const signed char* __restrict__ W8, int slotW, const float* __restrict__ bias,
    signed char* __restrict__ C8, int N, int K, u32* __restrict__ sc, int slotO,
    int colsPerSlot) {
  __shared__ __align__(16) u16 Ash[128 * 40];
  __shared__ __align__(16) u16 Asl[128 * 40];
  __shared__ __align__(16) u16 Bsh[192 * 40];
  __shared__ float red[4];
  const int tid = threadIdx.x;
  const long rowBase = (long)blockIdx.y * 128;
  const int colBase = blockIdx.x * 192;
  const float sW = read_max16(sc, slotW) / 127.0f + 1e-8f;

  const int lane = tid & 63, wv = tid >> 6;
  const int wm = wv >> 1, wn = wv & 1;
  const int fr = lane & 15, fk = lane >> 4;

  f32x4 acc[4][6];
#pragma unroll
  for (int m = 0; m < 4; ++m)
#pragma unroll
    for (int n = 0; n < 6; ++n) acc[m][n] = (f32x4){0.f, 0.f, 0.f, 0.f};

  const int arow = tid >> 1, ac2 = tid & 1;

  for (int k0 = 0; k0 < K; k0 += 32) {
    {
      const long g = (rowBase + arow) * (long)K + k0 + ac2 * 16;
      *(short8*)&Ash[arow * 40 + ac2 * 16] = *(const short8*)(Ahi + g);
      *(short8*)&Ash[arow * 40 + ac2 * 16 + 8] = *(const short8*)(Ahi + g + 8);
      *(short8*)&Asl[arow * 40 + ac2 * 16] = *(const short8*)(Alo + g);
      *(short8*)&Asl[arow * 40 + ac2 * 16 + 8] = *(const short8*)(Alo + g + 8);
    }
    if (tid < 192) {
      const signed char* wp = W8 + (long)(colBase + tid) * K + k0;
      int4 a = *(const int4*)wp;
      int4 b = *(const int4*)(wp + 16);
      *(short8*)&Bsh[tid * 40 + 0] = dec8(a.x, a.y);
      *(short8*)&Bsh[tid * 40 + 8] = dec8(a.z, a.w);
      *(short8*)&Bsh[tid * 40 + 16] = dec8(b.x, b.y);
      *(short8*)&Bsh[tid * 40 + 24] = dec8(b.z, b.w);
    }
    __syncthreads();
    short8 bf[6];
#pragma unroll
    for (int n = 0; n < 6; ++n)
      bf[n] = *(short8*)&Bsh[(wn * 96 + n * 16 + fr) * 40 + fk * 8];
#pragma unroll
    for (int m = 0; m < 4; ++m) {
      short8 ah = *(short8*)&Ash[(wm * 64 + m * 16 + fr) * 40 + fk * 8];
      short8 al = *(short8*)&Asl[(wm * 64 + m * 16 + fr) * 40 + fk * 8];
#pragma unroll
      for (int n = 0; n < 6; ++n) {
        acc[m][n] = MFMA16(ah, bf[n], acc[m][n]);
        acc[m][n] = MFMA16(al, bf[n], acc[m][n]);
      }
    }
    __syncthreads();
  }

  float sO = 1.f;
  if (OM == 2) sO = read_max16(sc, slotO + colBase / colsPerSlot) / 127.0f + 1e-8f;
  const float inv_sqrt2 = 0.70710678118654752440f;
  float vmax = 0.f;
#pragma unroll
  for (int n = 0; n < 6; ++n) {
    const int col = colBase + wn * 96 + n * 16 + fr;
    const float bb = bias[col];
#pragma unroll
    for (int m = 0; m < 4; ++m) {
#pragma unroll
      for (int r = 0; r < 4; ++r) {
        const long row = rowBase + wm * 64 + m * 16 + fk * 4 + r;
        float val = acc[m][n][r] * sW + bb;
        if (GELU) val = 0.5f * val * (1.0f + erff(val * inv_sqrt2));
        if (OM == 2) {
          float code = fminf(fmaxf(rintf(val / sO), -128.f), 127.f);
          C8[row * N + col] = (signed char)code;
        } else {
          vmax = fmaxf(vmax, fabsf(val));
        }
      }
    }
  }
  if (OM == 1) {
    float m = warpMax(vmax);
    if ((tid & 63) == 0) red[tid >> 6] = m;
    __syncthreads();
    if (tid == 0) {
      float r = fmaxf(fmaxf(red[0], red[1]), fmaxf(red[2], red[3]));
      atomicMax(sc + (slotO + colBase / colsPerSlot) * 16 + ((blockIdx.x + blockIdx.y) & 15),
                __float_as_uint(r));
    }
  }
}

// ---------------------------------------------------------------------------
// i8-MFMA GEMM (A = int8 codes): C = A8[M,K] · W8[N,K]^T * (sA*sW) + bias
// OM 1: absmax only; OM 3: H += fq(val, sO). BM=128 BN=192 BK=64.
// ---------------------------------------------------------------------------
template <int OM>
__global__ __launch_bounds__(256) void k_gemm8(
    const signed char* __restrict__ A8, int slotA, const signed char* __restrict__ W8,
    int slotW, const float* __restrict__ bias, float* __restrict__ H, int N, int K,
    u32* __restrict__ sc, int slotO) {
  __shared__ __align__(16) signed char As[128 * 80];
  __shared__ __align__(16) signed char Bs[192 * 80];
  __shared__ float red[4];
  const int tid = threadIdx.x;
  const long rowBase = (long)blockIdx.y * 128;
  const int colBase = blockIdx.x * 192;
  const float alpha = (read_max16(sc, slotA) / 127.0f + 1e-8f) *
                      (read_max16(sc, slotW) / 127.0f + 1e-8f);

  const int lane = tid & 63, wv = tid >> 6;
  const int wm = wv >> 1, wn = wv & 1;
  const int fr = lane & 15, fk = lane >> 4;

  int4v acc[4][6];
#pragma unroll
  for (int m = 0; m < 4; ++m)
#pragma unroll
    for (int n = 0; n < 6; ++n) acc[m][n] = (int4v){0, 0, 0, 0};

  const int arow = tid >> 1, ahalf = tid & 1;

  for (int k0 = 0; k0 < K; k0 += 64) {
    {
      const signed char* ap = A8 + (rowBase + arow) * (long)K + k0 + ahalf * 32;
      *(int4*)&As[arow * 80 + ahalf * 32] = *(const int4*)ap;
      *(int4*)&As[arow * 80 + ahalf * 32 + 16] = *(const int4*)(ap + 16);
    }
    if (tid < 192) {
      const signed char* wp = W8 + (long)(colBase + tid) * K + k0;
#pragma unroll
      for (int j = 0; j < 4; ++j)
        *(int4*)&Bs[tid * 80 + j * 16] = *(const int4*)(wp + j * 16);
    }
    __syncthreads();
    int4v bfr[6];
#pragma unroll
    for (int n = 0; n < 6; ++n)
      bfr[n] = *(const int4v*)&Bs[(wn * 96 + n * 16 + fr) * 80 + fk * 16];
#pragma unroll
    for (int m = 0; m < 4; ++m) {
      int4v af = *(const int4v*)&As[(wm * 64 + m * 16 + fr) * 80 + fk * 16];
#pragma unroll
      for (int n = 0; n < 6; ++n) acc[m][n] = MFMA_I8(af, bfr[n], acc[m][n]);
    }
    __syncthreads();
  }

  float sO = 1.f;
  if (OM == 3) sO = read_max16(sc, slotO) / 127.0f + 1e-8f;
  float vmax = 0.f;
#pragma unroll
  for (int n = 0; n < 6; ++n) {
    const int col = colBase + wn * 96 + n * 16 + fr;
    const float bb = bias[col];
#pragma unroll
    for (int m = 0; m < 4; ++m) {
#pragma unroll
      for (int r = 0; r < 4; ++r) {
        const long row = rowBase + wm * 64 + m * 16 + fk * 4 + r;
        float val = (float)acc[m][n][r] * alpha + bb;
        if (OM == 3) {
          H[row * N + col] += fqs(val, sO);
        } else {
          vmax = fmaxf(vmax, fabsf(val));
        }
      }
    }
  }
  if (OM == 1) {
    float m = warpMax(vmax);
    if ((tid & 63) == 0) red[tid >> 6] = m;
    __syncthreads();
    if (tid == 0) {
      float r = fmaxf(fmaxf(red[0], red[1]), fmaxf(red[2], red[3]));
      atomicMax(sc + slotO * 16 + ((blockIdx.x + blockIdx.y) & 15), __float_as_uint(r));
    }
  }
}

// ---------------------------------------------------------------------------
// k_vt: per (b,h), transpose V codes [400][64] -> VT8[bh][64][400] + colsumV.
// ---------------------------------------------------------------------------
__global__ __launch_bounds__(256) void k_vt(const signed char* __restrict__ qkv8,
                                            signed char* __restrict__ vt8,
                                            int* __restrict__ colsum) {
  __shared__ __align__(16) signed char T[64 * 80];
  __shared__ int cs[64];
  const int tid = threadIdx.x;
  const int bh = blockIdx.x, b = bh / 3, hh = bh % 3;
  const signed char* vb = qkv8 + (long)b * 400 * 576 + hh * 64 + 384;
  if (tid < 64) cs[tid] = 0;
  const int d = tid >> 2, seg = tid & 3;
  for (int c0 = 0; c0 < 448; c0 += 64) {
    __syncthreads();
    {
      int trow = tid >> 2, c = tid & 3;
      int4 v = make_int4(0, 0, 0, 0);
      if (c0 + trow < 400) v = *(const int4*)(vb + (long)(c0 + trow) * 576 + c * 16);
      *(int4*)&T[trow * 80 + c * 16] = v;
    }
    __syncthreads();
    int4 outw;
    int ssum = 0;
    u32 pk[4];
#pragma unroll
    for (int j = 0; j < 4; ++j) {
      u32 p = 0;
#pragma unroll
      for (int e = 0; e < 4; ++e) {
        int t = seg * 16 + j * 4 + e;
        int v = (int)T[t * 80 + d];
        ssum += v;
        p |= ((u32)(v & 0xff)) << (8 * e);
      }
      pk[j] = p;
    }
    outw.x = (int)pk[0]; outw.y = (int)pk[1]; outw.z = (int)pk[2]; outw.w = (int)pk[3];
    if (c0 + seg * 16 < 400)
      *(int4*)&vt8[(long)bh * 25600 + d * 400 + c0 + seg * 16] = outw;
    atomicAdd(&cs[d], ssum);
  }
  __syncthreads();
  if (tid < 64) colsum[bh * 64 + tid] = cs[tid];
}

// ---------------------------------------------------------------------------
// Attention (i8 MFMA, scores computed transposed: C[t][q]).
// Block = 64 q rows of one (b,h), 256 thr / 4 waves; wave w owns q = 16w+fr.
// Per lane: q = fr (one), t = tf*16 + fk*4 + r (4 consecutive).
// ---------------------------------------------------------------------------
__global__ __launch_bounds__(256) void k_attn0(const signed char* __restrict__ qkv8,
                                               u32* __restrict__ sc, int slotQ, int slotSc) {
  __shared__ __align__(16) signed char Qs[64 * 80];
  __shared__ __align__(16) signed char Ks[128 * 80];
  __shared__ float red[4];
  const int tid = threadIdx.x;
  const int r0 = blockIdx.x * 64;
  const int bh = blockIdx.y, b = bh / 3, hh = bh % 3;
  const signed char* qb = qkv8 + (long)b * 400 * 576 + hh * 64;
  const signed char* kb = qb + 192;
  const float sQ = read_max16(sc, slotQ) / 127.0f + 1e-8f;
  const float sK = read_max16(sc, slotQ + 1) / 127.0f + 1e-8f;
  const float sSc = sQ * sK * 0.125f;

  {
    int row = tid >> 2, c = tid & 3;
    int4 v = make_int4(0, 0, 0, 0);
    if (r0 + row < 400) v = *(const int4*)(qb + (long)(r0 + row) * 576 + c * 16);
    *(int4*)&Qs[row * 80 + c * 16] = v;
  }
  const int lane = tid & 63, w = tid >> 6, fr = lane & 15, fk = lane >> 4;
  __syncthreads();
  int4v qf = *(const int4v*)&Qs[(16 * w + fr) * 80 + fk * 16];

  float vmax = 0.f;
  for (int c0 = 0; c0 < 400; c0 += 128) {
    __syncthreads();
    {
      int trow = tid >> 1, half = tid & 1;
      int4 v0 = make_int4(0, 0, 0, 0), v1 = v0;
      if (c0 + trow < 400) {
        const signed char* kr = kb + (long)(c0 + trow) * 576 + half * 32;
        v0 = *(const int4*)kr;
        v1 = *(const int4*)(kr + 16);
      }
      *(int4*)&Ks[trow * 80 + half * 32] = v0;
      *(int4*)&Ks[trow * 80 + half * 32 + 16] = v1;
    }
    __syncthreads();
#pragma unroll
    for (int tf = 0; tf < 8; ++tf) {
      int4v kf = *(const int4v*)&Ks[(tf * 16 + fr) * 80 + fk * 16];
      int4v s = MFMA_I8(kf, qf, ((int4v){0, 0, 0, 0}));
#pragma unroll
      for (int r = 0; r < 4; ++r) vmax = fmaxf(vmax, fabsf((float)s[r]));
    }
  }
  float m = warpMax(vmax * sSc);
  if (lane == 0) red[w] = m;
  __syncthreads();
  if (tid == 0) {
    float r = fmaxf(fmaxf(red[0], red[1]), fmaxf(red[2], red[3]));
    atomicMax(sc + slotSc * 16 + ((blockIdx.x + blockIdx.y) & 15), __float_as_uint(r));
  }
}

__global__ __launch_bounds__(256) void k_attn1(const signed char* __restrict__ qkv8,
                                               float* __restrict__ gm, float* __restrict__ gl,
                                               u32* __restrict__ sc, int slotQ, int slotSc,
                                               int slotPr) {
  __shared__ __align__(16) signed char Qs[64 * 80];
  __shared__ __align__(16) signed char Ks[128 * 80];
  __shared__ __align__(16) signed char P8[64 * 432];
  __shared__ float red[4];
  const int tid = threadIdx.x;
  const int r0 = blockIdx.x * 64;
  const int bh = blockIdx.y, b = bh / 3, hh = bh % 3;
  const signed char* qb = qkv8 + (long)b * 400 * 576 + hh * 64;
  const signed char* kb = qb + 192;
  const float sQ = read_max16(sc, slotQ) / 127.0f + 1e-8f;
  const float sK = read_max16(sc, slotQ + 1) / 127.0f + 1e-8f;
  const float sSc = sQ * sK * 0.125f;
  const float sS = read_max16(sc, slotSc) / 127.0f + 1e-8f;

  {
    int row = tid >> 2, c = tid & 3;
    int4 v = make_int4(0, 0, 0, 0);
    if (r0 + row < 400) v = *(const int4*)(qb + (long)(r0 + row) * 576 + c * 16);
    *(int4*)&Qs[row * 80 + c * 16] = v;
  }
  const int lane = tid & 63, w = tid >> 6, fr = lane & 15, fk = lane >> 4;
  __syncthreads();
  int4v qf = *(const int4v*)&Qs[(16 * w + fr) * 80 + fk * 16];

  float cm = -1e30f;
  const int qloc = 16 * w + fr;

  for (int c0 = 0; c0 < 400; c0 += 128) {
    __syncthreads();
    {
      int trow = tid >> 1, half = tid & 1;
      int4 v0 = make_int4(0, 0, 0, 0), v1 = v0;
      if (c0 + trow < 400) {
        const signed char* kr = kb + (long)(c0 + trow) * 576 + half * 32;
        v0 = *(const int4*)kr;
        v1 = *(const int4*)(kr + 16);
      }
      *(int4*)&Ks[trow * 80 + half * 32] = v0;
      *(int4*)&Ks[trow * 80 + half * 32 + 16] = v1;
    }
    __syncthreads();
#pragma unroll
    for (int tf = 0; tf < 8; ++tf) {
      int4v kf = *(const int4v*)&Ks[(tf * 16 + fr) * 80 + fk * 16];
      int4v s = MFMA_I8(kf, qf, ((int4v){0, 0, 0, 0}));
      const int tbase = c0 + tf * 16 + fk * 4;
      if (tbase < 400) {
        u32 pack = 0;
#pragma unroll
        for (int r = 0; r < 4; ++r) {
          float cf = fminf(fmaxf(rintf(((float)s[r] * sSc) / sS), -128.f), 127.f);
          cm = fmaxf(cm, cf);
          pack |= ((u32)((int)cf & 0xff)) << (8 * r);
        }
        *(u32*)&P8[qloc * 432 + tbase] = pack;
      }
    }
  }
  // row max over the 4 fk-lanes sharing q
  cm = fmaxf(cm, __shfl_xor(cm, 16));
  cm = fmaxf(cm, __shfl_xor(cm, 32));
  const float rowm = cm * sS;
  __syncthreads();
  // flat exp sum: 4 lanes per row, u32 = 4 codes per read
  float sum = 0.f;
  for (int t4 = fk * 4; t4 < 400; t4 += 16) {
    u32 pk = *(const u32*)&P8[qloc * 432 + t4];
#pragma unroll
    for (int e = 0; e < 4; ++e)
      sum += expf((float)(signed char)(pk >> (8 * e)) * sS - rowm);
  }
  sum += __shfl_xor(sum, 16);
  sum += __shfl_xor(sum, 32);
  float cand = 0.f;
  const int gq = r0 + qloc;
  if (fk == 0 && gq < 400) {
    gm[(long)bh * 400 + gq] = rowm;
    gl[(long)bh * 400 + gq] = sum;
    cand = 1.0f / sum;
  }
  float m = warpMax(cand);
  if (lane == 0) red[w] = m;
  __syncthreads();
  if (tid == 0) {
    float r = fmaxf(fmaxf(red[0], red[1]), fmaxf(red[2], red[3]));
    atomicMax(sc + slotPr * 16 + ((blockIdx.x + blockIdx.y) & 15), __float_as_uint(r));
  }
}

// PV: probs -> (p-128) i8 codes -> out^T = VT·P'^T + 128*colsumV; ctx + absmax.
__global__ __launch_bounds__(256) void k_attn_pv(
    const signed char* __restrict__ qkv8, const signed char* __restrict__ vt8,
    const int* __restrict__ colsumV, float* __restrict__ ctx, const float* __restrict__ gm,
    const float* __restrict__ gl, u32* __restrict__ sc, int slotQ, int slotSc, int slotPr,
    int slotCtx) {
  __shared__ __align__(16) signed char Qs[64 * 80];
  __shared__ __align__(16) signed char Ks[128 * 80];
  __shared__ __align__(16) signed char Vs[64 * 144];
  __shared__ __align__(16) signed char Ps[64 * 144];
  __shared__ int colsV[64];
  __shared__ float red[4];
  const int tid = threadIdx.x;
  const int r0 = blockIdx.x * 64;
  const int bh = blockIdx.y, b = bh / 3, hh = bh % 3;
  const signed char* qb = qkv8 + (long)b * 400 * 576 + hh * 64;
  const signed char* kb = qb + 192;
  const signed char* vtb = vt8 + (long)bh * 25600;
  const float sQ = read_max16(sc, slotQ) / 127.0f + 1e-8f;
  const float sK = read_max16(sc, slotQ + 1) / 127.0f + 1e-8f;
  const float sV = read_max16(sc, slotQ + 2) / 127.0f + 1e-8f;
  const float sSc = sQ * sK * 0.125f;
  const float sS = read_max16(sc, slotSc) / 127.0f + 1e-8f;
  const float sP = read_max16(sc, slotPr) / 255.0f + 1e-8f;
  const float sPV = sP * sV;

  {
    int row = tid >> 2, c = tid & 3;
    int4 v = make_int4(0, 0, 0, 0);
    if (r0 + row < 400) v = *(const int4*)(qb + (long)(r0 + row) * 576 + c * 16);
    *(int4*)&Qs[row * 80 + c * 16] = v;
  }
  if (tid < 64) colsV[tid] = colsumV[bh * 64 + tid];
  const int lane = tid & 63, w = tid >> 6, fr = lane & 15, fk = lane >> 4;
  __syncthreads();
  int4v qf = *(const int4v*)&Qs[(16 * w + fr) * 80 + fk * 16];

  const int qloc = 16 * w + fr;
  int gq = r0 + qloc;
  if (gq > 399) gq = 399;
  const float rowm = gm[(long)bh * 400 + gq];
  const float rowl = gl[(long)bh * 400 + gq];

  int4v accd[4];
#pragma unroll
  for (int dt = 0; dt < 4; ++dt) accd[dt] = (int4v){0, 0, 0, 0};

  for (int c0 = 0; c0 < 400; c0 += 128) {
    __syncthreads();
    {  // K chunk
      int trow = tid >> 1, half = tid & 1;
      int4 v0 = make_int4(0, 0, 0, 0), v1 = v0;
      if (c0 + trow < 400) {
        const signed char* kr = kb + (long)(c0 + trow) * 576 + half * 32;
        v0 = *(const int4*)kr;
        v1 = *(const int4*)(kr + 16);
      }
      *(int4*)&Ks[trow * 80 + half * 32] = v0;
      *(int4*)&Ks[trow * 80 + half * 32 + 16] = v1;
    }
    {  // V^T chunk: rows d (64), cols t (128)
      int d = tid >> 2, seg = tid & 3;
      int t0 = c0 + seg * 32;
      int4 u0 = make_int4(0, 0, 0, 0), u1 = u0;
      if (t0 < 400) u0 = *(const int4*)(vtb + d * 400 + t0);
      if (t0 + 16 < 400) u1 = *(const int4*)(vtb + d * 400 + t0 + 16);
      *(int4*)&Vs[d * 144 + seg * 32] = u0;
      *(int4*)&Vs[d * 144 + seg * 32 + 16] = u1;
    }
    __syncthreads();
    // scores -> P' codes
#pragma unroll
    for (int tf = 0; tf < 8; ++tf) {
      int4v kf = *(const int4v*)&Ks[(tf * 16 + fr) * 80 + fk * 16];
      int4v s = MFMA_I8(kf, qf, ((int4v){0, 0, 0, 0}));
      const int tbase = c0 + tf * 16 + fk * 4;
      u32 pack = 0;
      if (tbase < 400) {
#pragma unroll
        for (int r = 0; r < 4; ++r) {
          float cf = fminf(fmaxf(rintf(((float)s[r] * sSc) / sS), -128.f), 127.f);
          float qv = cf * sS;
          float p = expf(qv - rowm) / rowl;
          float pu = fminf(fmaxf(rintf(p / sP), 0.f), 255.f);
          int pc = (int)pu - 128;
          pack |= ((u32)(pc & 0xff)) << (8 * r);
        }
      }
      *(u32*)&Ps[qloc * 144 + tf * 16 + fk * 4] = pack;
    }
    __syncthreads();
    // PV: 2 k-steps of 64 t
    int4v pf0 = *(const int4v*)&Ps[qloc * 144 + fk * 16];
    int4v pf1 = *(const int4v*)&Ps[qloc * 144 + 64 + fk * 16];
#pragma unroll
    for (int dt = 0; dt < 4; ++dt) {
      int4v vf0 = *(const int4v*)&Vs[(dt * 16 + fr) * 144 + fk * 16];
      int4v vf1 = *(const int4v*)&Vs[(dt * 16 + fr) * 144 + 64 + fk * 16];
      accd[dt] = MFMA_I8(vf0, pf0, accd[dt]);
      accd[dt] = MFMA_I8(vf1, pf1, accd[dt]);
    }
  }
  // epilogue: lane holds 4 d (fk*4+r within dt-tile) for q = r0+qloc
  float vmax = 0.f;
  const int q = r0 + qloc;
  if (q < 400) {
#pragma unroll
    for (int dt = 0; dt < 4; ++dt) {
      const int d0 = dt * 16 + fk * 4;
      float4 o;
      o.x = sPV * (float)(accd[dt][0] + 128 * colsV[d0 + 0]);
      o.y = sPV * (float)(accd[dt][1] + 128 * colsV[d0 + 1]);
      o.z = sPV * (float)(accd[dt][2] + 128 * colsV[d0 + 2]);
      o.w = sPV * (float)(accd[dt][3] + 128 * colsV[d0 + 3]);
      vmax = fmaxf(vmax, fmaxf(fmaxf(fabsf(o.x), fabsf(o.y)), fmaxf(fabsf(o.z), fabsf(o.w))));
      *(float4*)&ctx[(long)(b * 400 + q) * 192 + hh * 64 + d0] = o;
    }
  }
  float m = warpMax(vmax);
  if (lane == 0) red[w] = m;
  __syncthreads();
  if (tid == 0) {
    float r = fmaxf(fmaxf(red[0], red[1]), fmaxf(red[2], red[3]));
    atomicMax(sc + slotCtx * 16 + ((blockIdx.x + blockIdx.y) & 15), __float_as_uint(r));
  }
}

// ---------------------------------------------------------------------------
// final pool + logits
// ---------------------------------------------------------------------------
__global__ __launch_bounds__(192) void k_pool(const float* __restrict__ xln,
                                              float* __restrict__ pooled,
                                              u32* __restrict__ slot) {
  int b = blockIdx.x, d = threadIdx.x;
  float sum = 0.f;
  for (int s = 0; s < 400; ++s) sum += xln[((long)b * 400 + s) * 192 + d];
  float v = sum / 400.0f;
  pooled[(long)b * 192 + d] = v;
  __shared__ float red[3];
  float m = warpMax(fabsf(v));
  if ((d & 63) == 0) red[d >> 6] = m;
  __syncthreads();
  if (d == 0)
    atomicMax(slot + (b & 15), __float_as_uint(fmaxf(fmaxf(red[0], red[1]), red[2])));
}

__global__ __launch_bounds__(64) void k_logits(const float* __restrict__ pooled,
                                               const float* __restrict__ clfq,
                                               const float* __restrict__ clfb,
                                               const u32* __restrict__ sc,
                                               float* __restrict__ out) {
  int c = blockIdx.x, b = blockIdx.y, lane = threadIdx.x;
  float sp = read_max16(sc, SLOT_POOL) / 127.0f + 1e-8f;
  float acc = 0.f;
#pragma unroll
  for (int j = 0; j < 3; ++j) {
    int d = lane + 64 * j;
    acc += fqs(pooled[(long)b * 192 + d], sp) * clfq[c * 192 + d];
  }
#pragma unroll
  for (int o = 32; o > 0; o >>= 1) acc += __shfl_down(acc, o);
  if (lane == 0) out[b * 7 + c] = acc + clfb[c];
}

// ---------------------------------------------------------------------------
// host
// ---------------------------------------------------------------------------
static inline int gsz(long n4, long cap) {
  long g = (n4 + 255) / 256;
  return (int)(g < cap ? g : cap);
}

extern "C" void kernel_launch(void* const* d_in, const int* in_sizes, int n_in,
                              void* d_out, int out_size, void* d_ws, size_t ws_size,
                              hipStream_t stream) {
  (void)in_sizes; (void)n_in; (void)out_size; (void)ws_size;

  const float* x = (const float*)d_in[0];
  const float* pw = (const float*)d_in[1];
  const float* pb = (const float*)d_in[2];
  const float* ln1g = (const float*)d_in[3];
  const float* ln1b = (const float*)d_in[4];
  const float* wqkv = (const float*)d_in[5];
  const float* bqkv = (const float*)d_in[6];
  const float* wo = (const float*)d_in[7];
  const float* bo = (const float*)d_in[8];
  const float* ln2g = (const float*)d_in[9];
  const float* ln2b = (const float*)d_in[10];
  const float* w1 = (const float*)d_in[11];
  const float* b1 = (const float*)d_in[12];
  const float* w2 = (const float*)d_in[13];
  const float* b2 = (const float*)d_in[14];
  const float* lnfg = (const float*)d_in[15];
  const float* lnfb = (const float*)d_in[16];
  const float* clfw = (const float*)d_in[17];
  const float* clfb = (const float*)d_in[18];

  float* ws = (float*)d_ws;
  u32* sc = (u32*)d_ws;
  float* GM = ws + OFF_GM;
  float* GL = ws + OFF_GL;
  float* POOL = ws + OFF_POOL;
  float* PWQ = ws + OFF_PWQ;
  float* CLFQ = ws + OFF_CLFQ;
  float* H = ws + OFF_H;
  float* Af = ws + OFF_A;        // fp32 view of A region (ctx / final LN out)
  u16* XH = (u16*)(ws + OFF_A);  // hi plane
  u16* XL = XH + 19660800;       // lo plane
  signed char* U8 = (signed char*)(ws + OFF_U);
  signed char* VT8 = U8 + 58982400;           // 19,660,800 B = V^T codes
  int* COLSUM = (int*)POOL;                   // 768*64 i32 (after WQC's last use)
  // weight-code scratch (regions idle at those times)
  signed char* WQC = (signed char*)POOL;      // 110592 B (POOL region)
  signed char* WOC = (signed char*)GM;        // 36864 B
  signed char* W1C = WOC + 36864;             // 147456 B
  signed char* W2C = W1C + 147456;            // 147456 B (all within GM region)
  float* out = (float*)d_out;

  k_zero<<<(N_SLOT_WORDS + 255) / 256, 256, 0, stream>>>(sc, N_SLOT_WORDS);

  auto amax = [&](const float* p, long n, int slot) {
    k_absmax<<<gsz(n / 4, 256), 256, 0, stream>>>((const float4*)p, n / 4, sc + slot * 16);
  };
  amax(pw, 3840, SLOT_PW);
  amax(clfw, 1344, SLOT_CLF);
  amax(x, 2048000, SLOT_X);
  for (int i = 0; i < NL; ++i) {
    int Lb = 16 + i * 16;
    amax(wqkv + (long)i * 110592, 110592, Lb + 0);
    amax(wo + (long)i * 36864, 36864, Lb + 1);
    amax(w1 + (long)i * 147456, 147456, Lb + 2);
    amax(w2 + (long)i * 147456, 147456, Lb + 3);
  }
  k_quant4<<<gsz(960, 256), 256, 0, stream>>>((const float4*)pw, (float4*)PWQ, 960, sc, SLOT_PW);
  k_quant4<<<gsz(336, 256), 256, 0, stream>>>((const float4*)clfw, (float4*)CLFQ, 336, sc,
                                              SLOT_CLF);

  // patch embed -> Af -> quant into H; first LN -> planes
  k_patch<<<12800, 192, 0, stream>>>(x, PWQ, pb, sc, Af, sc + SLOT_EMB * 16);
  k_quant4<<<2048, 256, 0, stream>>>((const float4*)Af, (float4*)H, 19660800 / 4, sc, SLOT_EMB);
  k_ln<true><<<(int)(ROWS / 4), 256, 0, stream>>>(H, ln1g, ln1b, XH, XL, nullptr, (int)ROWS);

  for (int i = 0; i < NL; ++i) {
    int Lb = 16 + i * 16;
    // --- attention ---
    k_wquant<<<108, 256, 0, stream>>>((const float4*)(wqkv + (long)i * 110592), (u32*)WQC,
                                      27648, sc, Lb + 0);
    {
      dim3 g(3, 800);
      k_gemmA<false, 1><<<g, 256, 0, stream>>>(XH, XL, WQC, Lb + 0, bqkv + i * 576, nullptr,
                                               576, 192, sc, Lb + 4, 192);
      k_gemmA<false, 2><<<g, 256, 0, stream>>>(XH, XL, WQC, Lb + 0, bqkv + i * 576, U8, 576,
                                               192, sc, Lb + 4, 192);
    }
    k_vt<<<768, 256, 0, stream>>>(U8, VT8, COLSUM);
    {
      dim3 ga(7, 768);
      k_attn0<<<ga, 256, 0, stream>>>(U8, sc, Lb + 4, Lb + 7);
      k_attn1<<<ga, 256, 0, stream>>>(U8, GM, GL, sc, Lb + 4, Lb + 7, Lb + 8);
      k_attn_pv<<<ga, 256, 0, stream>>>(U8, VT8, COLSUM, Af, GM, GL, sc, Lb + 4, Lb + 7,
                                        Lb + 8, Lb + 9);
    }
    // ctx fp32 (Af) -> int8 codes (U8 head); weight codes for wo/w1/w2
    k_quant_codes<<<2048, 256, 0, stream>>>((const float4*)Af, (u32*)U8, 19660800 / 4, sc,
                                            Lb + 9);
    k_wquant<<<36, 256, 0, stream>>>((const float4*)(wo + (long)i * 36864), (u32*)WOC, 9216,
                                     sc, Lb + 1);
    k_wquant<<<144, 256, 0, stream>>>((const float4*)(w1 + (long)i * 147456), (u32*)W1C, 36864,
                                      sc, Lb + 2);
    k_wquant<<<144, 256, 0, stream>>>((const float4*)(w2 + (long)i * 147456), (u32*)W2C, 36864,
                                      sc, Lb + 3);
    {
      dim3 g(1, 800);
      k_gemm8<1><<<g, 256, 0, stream>>>(U8, Lb + 9, WOC, Lb + 1, bo + i * 192, nullptr, 192,
                                        192, sc, Lb + 10);
      k_gemm8<3><<<g, 256, 0, stream>>>(U8, Lb + 9, WOC, Lb + 1, bo + i * 192, H, 192, 192, sc,
                                        Lb + 10);
    }
    // LN2 -> planes
    k_ln<true><<<(int)(ROWS / 4), 256, 0, stream>>>(H, ln2g + i * 192, ln2b + i * 192, XH, XL,
                                                    nullptr, (int)ROWS);
    // --- MLP ---
    {
      dim3 g(4, 800);
      k_gemmA<true, 1><<<g, 256, 0, stream>>>(XH, XL, W1C, Lb + 2, b1 + i * 768, nullptr, 768,
                                              192, sc, Lb + 11, 768);
      k_gemmA<true, 2><<<g, 256, 0, stream>>>(XH, XL, W1C, Lb + 2, b1 + i * 768, U8, 768, 192,
                                              sc, Lb + 11, 768);
    }
    {
      dim3 g(1, 800);
      k_gemm8<1><<<g, 256, 0, stream>>>(U8, Lb + 11, W2C, Lb + 3, b2 + i * 192, nullptr, 192,
                                        768, sc, Lb + 12);
      k_gemm8<3><<<g, 256, 0, stream>>>(U8, Lb + 11, W2C, Lb + 3, b2 + i * 192, H, 192, 768,
                                        sc, Lb + 12);
    }
    // next LN (ln1 of i+1) or final LN -> fp32 into Af
    if (i < NL - 1) {
      k_ln<true><<<(int)(ROWS / 4), 256, 0, stream>>>(H, ln1g + (i + 1) * 192,
                                                      ln1b + (i + 1) * 192, XH, XL, nullptr,
                                                      (int)ROWS);
    } else {
      k_ln<false><<<(int)(ROWS / 4), 256, 0, stream>>>(H, lnfg, lnfb, nullptr, nullptr, Af,
                                                       (int)ROWS);
    }
  }

  // pool + classifier
  k_pool<<<256, 192, 0, stream>>>(Af, POOL, sc + SLOT_POOL * 16);
  {
    dim3 g(7, 256);
    k_logits<<<g, 64, 0, stream>>>(POOL, CLFQ, clfb, sc, out);
  }
}

// Round 7
// 8220.676 us; speedup vs baseline: 1.4265x; 1.2453x over previous
//
#include <hip/hip_runtime.h>
#include <math.h>

// ---------------------------------------------------------------------------
// TinyMyo 8ch/400tok quant transformer — v6: VALU-lean attention.
// exp2-based softmax, folded reciprocals, row-int-max from phase0,
// XCD-chunked block swizzle. Integer MFMA accumulation exact (<2^24).
// ---------------------------------------------------------------------------

typedef unsigned int u32;
typedef unsigned short u16;
typedef __attribute__((ext_vector_type(8))) short short8;
typedef __attribute__((ext_vector_type(4))) float f32x4;
typedef __attribute__((ext_vector_type(4))) int int4v;

#define MFMA16(a, b, c) __builtin_amdgcn_mfma_f32_16x16x32_bf16((a), (b), (c), 0, 0, 0)
#define MFMA_I8(a, b, c) __builtin_amdgcn_mfma_i32_16x16x64_i8((a), (b), (c), 0, 0, 0)

constexpr int NL = 8;
constexpr long ROWS = 102400;  // B*SEQ
constexpr float LOG2E = 1.44269504088896340736f;

// ---- scale slots (each 16 shadow u32 words) ----
constexpr int SLOT_X = 0, SLOT_PW = 1, SLOT_EMB = 2, SLOT_CLF = 3, SLOT_POOL = 4;
constexpr int N_SLOT_WORDS = 200 * 16;

// ---- ws layout (float units), total 59,653,536 floats = 238.6 MB ----
constexpr long OFF_GM = 3200;
constexpr long OFF_GL = OFF_GM + 307200;
constexpr long OFF_POOL = OFF_GL + 307200;
constexpr long OFF_PWQ = OFF_POOL + 49152;
constexpr long OFF_CLFQ = OFF_PWQ + 3840;
constexpr long OFF_H = OFF_CLFQ + 1344;
constexpr long OFF_A = OFF_H + 19660800;
constexpr long OFF_U = OFF_A + 19660800;

// ---------------------------------------------------------------------------
// helpers
// ---------------------------------------------------------------------------
__device__ __forceinline__ float warpMax(float v) {
#pragma unroll
  for (int o = 32; o > 0; o >>= 1) v = fmaxf(v, __shfl_down(v, o));
  return v;
}

__device__ __forceinline__ float read_max16(const u32* sc, int slot) {
  const u32* p = sc + slot * 16;
  u32 m = 0;
#pragma unroll
  for (int i = 0; i < 16; ++i) m = max(m, p[i]);
  return __uint_as_float(m);
}

__device__ __forceinline__ float fqs(float x, float s) {
  return fminf(fmaxf(rintf(x / s), -128.0f), 127.0f) * s;
}

__device__ __forceinline__ float bf2f(u16 h) { return __uint_as_float(((u32)h) << 16); }
__device__ __forceinline__ u16 f2bf(float f) {
  u32 b = __float_as_uint(f);
  return (u16)((b + 0x7FFFu + ((b >> 16) & 1u)) >> 16);
}
__device__ __forceinline__ short i2bf(float v) { return (short)(u16)(__float_as_uint(v) >> 16); }
__device__ __forceinline__ short8 dec8(int lo, int hi) {
  short8 o;
#pragma unroll
  for (int j = 0; j < 4; ++j) {
    o[j] = i2bf((float)((signed char)(lo >> (8 * j))));
    o[j + 4] = i2bf((float)((signed char)(hi >> (8 * j))));
  }
  return o;
}

// ---------------------------------------------------------------------------
// small utility kernels
// ---------------------------------------------------------------------------
__global__ void k_zero(u32* p, int n) {
  int i = blockIdx.x * blockDim.x + threadIdx.x;
  if (i < n) p[i] = 0u;
}

__global__ __launch_bounds__(256) void k_absmax(const float4* __restrict__ x, long n4,
                                                u32* __restrict__ slot) {
  float m = 0.f;
  for (long i = (long)blockIdx.x * blockDim.x + threadIdx.x; i < n4;
       i += (long)gridDim.x * blockDim.x) {
    float4 v = x[i];
    m = fmaxf(m, fmaxf(fmaxf(fabsf(v.x), fabsf(v.y)), fmaxf(fabsf(v.z), fabsf(v.w))));
  }
  __shared__ float red[4];
  m = warpMax(m);
  int lane = threadIdx.x & 63, w = threadIdx.x >> 6;
  if (lane == 0) red[w] = m;
  __syncthreads();
  if (threadIdx.x == 0) {
    float r = fmaxf(fmaxf(red[0], red[1]), fmaxf(red[2], red[3]));
    atomicMax(slot + (blockIdx.x & 15), __float_as_uint(r));
  }
}

__global__ __launch_bounds__(256) void k_quant4(const float4* __restrict__ in,
                                                float4* __restrict__ out, long n4,
                                                const u32* __restrict__ sc, int slot) {
  float s = read_max16(sc, slot) / 127.0f + 1e-8f;
  for (long i = (long)blockIdx.x * blockDim.x + threadIdx.x; i < n4;
       i += (long)gridDim.x * blockDim.x) {
    float4 v = in[i];
    v.x = fqs(v.x, s); v.y = fqs(v.y, s); v.z = fqs(v.z, s); v.w = fqs(v.w, s);
    out[i] = v;
  }
}

__global__ __launch_bounds__(256) void k_quant_codes(const float4* __restrict__ in,
                                                     u32* __restrict__ out, long n4,
                                                     const u32* __restrict__ sc, int slot) {
  float s = read_max16(sc, slot) / 127.0f + 1e-8f;
  for (long i = (long)blockIdx.x * blockDim.x + threadIdx.x; i < n4;
       i += (long)gridDim.x * blockDim.x) {
    float4 v = in[i];
    int c0 = (int)fminf(fmaxf(rintf(v.x / s), -128.f), 127.f);
    int c1 = (int)fminf(fmaxf(rintf(v.y / s), -128.f), 127.f);
    int c2 = (int)fminf(fmaxf(rintf(v.z / s), -128.f), 127.f);
    int c3 = (int)fminf(fmaxf(rintf(v.w / s), -128.f), 127.f);
    out[i] = (u32)(c0 & 0xff) | ((u32)(c1 & 0xff) << 8) | ((u32)(c2 & 0xff) << 16) |
             ((u32)(c3 & 0xff) << 24);
  }
}

// ---------------------------------------------------------------------------
// patch embed
// ---------------------------------------------------------------------------
__global__ __launch_bounds__(192) void k_patch(const float* __restrict__ x,
                                               const float* __restrict__ pwq,
                                               const float* __restrict__ pb,
                                               const u32* __restrict__ sc,
                                               float* __restrict__ emb,
                                               u32* __restrict__ embSlot) {
  __shared__ float xq[8][20];
  __shared__ float red[3];
  const int tid = threadIdx.x;
  const long rowBase = (long)blockIdx.x * 8;
  const float sx = read_max16(sc, SLOT_X) / 127.0f + 1e-8f;
  if (tid < 160) {
    int r = tid / 20, k = tid % 20;
    xq[r][k] = fqs(x[(rowBase + r) * 20 + k], sx);
  }
  __syncthreads();
  float wreg[20];
#pragma unroll
  for (int k = 0; k < 20; ++k) wreg[k] = pwq[tid * 20 + k];
  const float bias = pb[tid];
  float m = 0.f;
  for (int r = 0; r < 8; ++r) {
    float acc = bias;
#pragma unroll
    for (int k = 0; k < 20; ++k) acc += xq[r][k] * wreg[k];
    emb[(rowBase + r) * 192 + tid] = acc;
    m = fmaxf(m, fabsf(acc));
  }
  m = warpMax(m);
  if ((tid & 63) == 0) red[tid >> 6] = m;
  __syncthreads();
  if (tid == 0)
    atomicMax(embSlot + (blockIdx.x & 15),
              __float_as_uint(fmaxf(fmaxf(red[0], red[1]), red[2])));
}

// ---------------------------------------------------------------------------
// LayerNorm (reads only H). HILO -> hi/lo bf16 planes, else fp32.
// ---------------------------------------------------------------------------
template <bool HILO>
__global__ __launch_bounds__(256) void k_ln(const float* __restrict__ x,
                                            const float* __restrict__ g,
                                            const float* __restrict__ bta,
                                            u16* __restrict__ yh, u16* __restrict__ yl,
                                            float* __restrict__ yf, int rows) {
  int w = threadIdx.x >> 6, lane = threadIdx.x & 63;
  long row = (long)blockIdx.x * 4 + w;
  if (row >= rows) return;
  const float* xr = x + row * 192;
  float v0 = xr[lane], v1 = xr[lane + 64], v2 = xr[lane + 128];
  float s = v0 + v1 + v2;
#pragma unroll
  for (int o = 32; o > 0; o >>= 1) s += __shfl_down(s, o);
  s = __shfl(s, 0);
  float mean = s / 192.0f;
  float d0 = v0 - mean, d1 = v1 - mean, d2 = v2 - mean;
  float q = d0 * d0 + d1 * d1 + d2 * d2;
#pragma unroll
  for (int o = 32; o > 0; o >>= 1) q += __shfl_down(q, o);
  q = __shfl(q, 0);
  float rs = 1.0f / sqrtf(q / 192.0f + 1e-5f);
  float o0 = d0 * rs * g[lane] + bta[lane];
  float o1 = d1 * rs * g[lane + 64] + bta[lane + 64];
  float o2 = d2 * rs * g[lane + 128] + bta[lane + 128];
  if (HILO) {
    long b = row * 192;
    u16 h0 = f2bf(o0), h1 = f2bf(o1), h2 = f2bf(o2);
    yh[b + lane] = h0;       yl[b + lane] = f2bf(o0 - bf2f(h0));
    yh[b + lane + 64] = h1;  yl[b + lane + 64] = f2bf(o1 - bf2f(h1));
    yh[b + lane + 128] = h2; yl[b + lane + 128] = f2bf(o2 - bf2f(h2));
  } else {
    float* yr = yf + row * 192;
    yr[lane] = o0; yr[lane + 64] = o1; yr[lane + 128] = o2;
  }
}

// ---------------------------------------------------------------------------
// weight fp32 -> int8 codes
// ---------------------------------------------------------------------------
__global__ __launch_bounds__(256) void k_wquant(const float4* __restrict__ w,
                                                u32* __restrict__ out, int n4,
                                                const u32* __restrict__ sc, int slot) {
  int i = blockIdx.x * blockDim.x + threadIdx.x;
  if (i >= n4) return;
  float s = read_max16(sc, slot) / 127.0f + 1e-8f;
  float4 v = w[i];
  int c0 = (int)fminf(fmaxf(rintf(v.x / s), -128.f), 127.f);
  int c1 = (int)fminf(fmaxf(rintf(v.y / s), -128.f), 127.f);
  int c2 = (int)fminf(fmaxf(rintf(v.z / s), -128.f), 127.f);
  int c3 = (int)fminf(fmaxf(rintf(v.w / s), -128.f), 127.f);
  out[i] = (u32)(c0 & 0xff) | ((u32)(c1 & 0xff) << 8) | ((u32)(c2 & 0xff) << 16) |
           ((u32)(c3 & 0xff) << 24);
}

// ---------------------------------------------------------------------------
// bf16-MFMA GEMM (fp32 A via hi/lo planes), 1D grid, XCD-chunked.
// vid col-fastest: bx = vid % ncol, by = vid / ncol.
// ---------------------------------------------------------------------------
template <bool GELU, int OM>
__global__ __launch_bounds__(256) void k_gemmA(
    const u16* __restrict__ Ahi, const u16* __restrict__ Alo,
    const signed char* __restrict__ W8, int slotW, const float* __restrict__ bias,
    signed char* __restrict__ C8, int N, int K, int ncol, u32* __restrict__ sc, int slotO,
    int colsPerSlot) {
  __shared__ __align__(16) u16 Ash[128 * 40];
  __shared__ __align__(16) u16 Asl[128 * 40];
  __shared__ __align__(16) u16 Bsh[192 * 40];
  __shared__ float red[4];
  const int tid = threadIdx.x;
  const int bid = blockIdx.x;
  const int vid = (bid & 7) * ((int)gridDim.x >> 3) + (bid >> 3);
  const int bx = vid % ncol;
  const long by = vid / ncol;
  const long rowBase = by * 128;
  const int colBase = bx * 192;
  const float sW = read_max16(sc, slotW) / 127.0f + 1e-8f;

  const int lane = tid & 63, wv = tid >> 6;
  const int wm = wv >> 1, wn = wv & 1;
  const int fr = lane & 15, fk = lane >> 4;

  f32x4 acc[4][6];
#pragma unroll
  for (int m = 0; m < 4; ++m)
#pragma unroll
    for (int n = 0; n < 6; ++n) acc[m][n] = (f32x4){0.f, 0.f, 0.f, 0.f};

  const int arow = tid >> 1, ac2 = tid & 1;

  for (int k0 = 0; k0 < K; k0 += 32) {
    {
      const long g = (rowBase + arow) * (long)K + k0 + ac2 * 16;
      *(short8*)&Ash[arow * 40 + ac2 * 16] = *(const short8*)(Ahi + g);
      *(short8*)&Ash[arow * 40 + ac2 * 16 + 8] = *(const short8*)(Ahi + g + 8);
      *(short8*)&Asl[arow * 40 + ac2 * 16] = *(const short8*)(Alo + g);
      *(short8*)&Asl[arow * 40 + ac2 * 16 + 8] = *(const short8*)(Alo + g + 8);
    }
    if (tid < 192) {
      const signed char* wp = W8 + (long)(colBase + tid) * K + k0;
      int4 a = *(const int4*)wp;
      int4 b = *(const int4*)(wp + 16);
      *(short8*)&Bsh[tid * 40 + 0] = dec8(a.x, a.y);
      *(short8*)&Bsh[tid * 40 + 8] = dec8(a.z, a.w);
      *(short8*)&Bsh[tid * 40 + 16] = dec8(b.x, b.y);
      *(short8*)&Bsh[tid * 40 + 24] = dec8(b.z, b.w);
    }
    __syncthreads();
    short8 bf[6];
#pragma unroll
    for (int n = 0; n < 6; ++n)
      bf[n] = *(short8*)&Bsh[(wn * 96 + n * 16 + fr) * 40 + fk * 8];
#pragma unroll
    for (int m = 0; m < 4; ++m) {
      short8 ah = *(short8*)&Ash[(wm * 64 + m * 16 + fr) * 40 + fk * 8];
      short8 al = *(short8*)&Asl[(wm * 64 + m * 16 + fr) * 40 + fk * 8];
#pragma unroll
      for (int n = 0; n < 6; ++n) {
        acc[m][n] = MFMA16(ah, bf[n], acc[m][n]);
        acc[m][n] = MFMA16(al, bf[n], acc[m][n]);
      }
    }
    __syncthreads();
  }

  float sO = 1.f;
  if (OM == 2) sO = read_max16(sc, slotO + colBase / colsPerSlot) / 127.0f + 1e-8f;
  const float inv_sqrt2 = 0.70710678118654752440f;
  float vmax = 0.f;
#pragma unroll
  for (int n = 0; n < 6; ++n) {
    const int col = colBase + wn * 96 + n * 16 + fr;
    const float bb = bias[col];
#pragma unroll
    for (int m = 0; m < 4; ++m) {
#pragma unroll
      for (int r = 0; r < 4; ++r) {
        const long row = rowBase + wm * 64 + m * 16 + fk * 4 + r;
        float val = acc[m][n][r] * sW + bb;
        if (GELU) val = 0.5f * val * (1.0f + erff(val * inv_sqrt2));
        if (OM == 2) {
          float code = fminf(fmaxf(rintf(val / sO), -128.f), 127.f);
          C8[row * N + col] = (signed char)code;
        } else {
          vmax = fmaxf(vmax, fabsf(val));
        }
      }
    }
  }
  if (OM == 1) {
    float m = warpMax(vmax);
    if ((tid & 63) == 0) red[tid >> 6] = m;
    __syncthreads();
    if (tid == 0) {
      float r = fmaxf(fmaxf(red[0], red[1]), fmaxf(red[2], red[3]));
      atomicMax(sc + (slotO + colBase / colsPerSlot) * 16 + ((int)(bx + by) & 15),
                __float_as_uint(r));
    }
  }
}

// ---------------------------------------------------------------------------
// i8-MFMA GEMM (A = int8 codes). Grid (1,800) unchanged.
// ---------------------------------------------------------------------------
template <int OM>
__global__ __launch_bounds__(256) void k_gemm8(
    const signed char* __restrict__ A8, int slotA, const signed char* __restrict__ W8,
    int slotW, const float* __restrict__ bias, float* __restrict__ H, int N, int K,
    u32* __restrict__ sc, int slotO) {
  __shared__ __align__(16) signed char As[128 * 80];
  __shared__ __align__(16) signed char Bs[192 * 80];
  __shared__ float red[4];
  const int tid = threadIdx.x;
  const long rowBase = (long)blockIdx.y * 128;
  const int colBase = blockIdx.x * 192;
  const float alpha = (read_max16(sc, slotA) / 127.0f + 1e-8f) *
                      (read_max16(sc, slotW) / 127.0f + 1e-8f);

  const int lane = tid & 63, wv = tid >> 6;
  const int wm = wv >> 1, wn = wv & 1;
  const int fr = lane & 15, fk = lane >> 4;

  int4v acc[4][6];
#pragma unroll
  for (int m = 0; m < 4; ++m)
#pragma unroll
    for (int n = 0; n < 6; ++n) acc[m][n] = (int4v){0, 0, 0, 0};

  const int arow = tid >> 1, ahalf = tid & 1;

  for (int k0 = 0; k0 < K; k0 += 64) {
    {
      const signed char* ap = A8 + (rowBase + arow) * (long)K + k0 + ahalf * 32;
      *(int4*)&As[arow * 80 + ahalf * 32] = *(const int4*)ap;
      *(int4*)&As[arow * 80 + ahalf * 32 + 16] = *(const int4*)(ap + 16);
    }
    if (tid < 192) {
      const signed char* wp = W8 + (long)(colBase + tid) * K + k0;
#pragma unroll
      for (int j = 0; j < 4; ++j)
        *(int4*)&Bs[tid * 80 + j * 16] = *(const int4*)(wp + j * 16);
    }
    __syncthreads();
    int4v bfr[6];
#pragma unroll
    for (int n = 0; n < 6; ++n)
      bfr[n] = *(const int4v*)&Bs[(wn * 96 + n * 16 + fr) * 80 + fk * 16];
#pragma unroll
    for (int m = 0; m < 4; ++m) {
      int4v af = *(const int4v*)&As[(wm * 64 + m * 16 + fr) * 80 + fk * 16];
#pragma unroll
      for (int n = 0; n < 6; ++n) acc[m][n] = MFMA_I8(af, bfr[n], acc[m][n]);
    }
    __syncthreads();
  }

  float sO = 1.f;
  if (OM == 3) sO = read_max16(sc, slotO) / 127.0f + 1e-8f;
  float vmax = 0.f;
#pragma unroll
  for (int n = 0; n < 6; ++n) {
    const int col = colBase + wn * 96 + n * 16 + fr;
    const float bb = bias[col];
#pragma unroll
    for (int m = 0; m < 4; ++m) {
#pragma unroll
      for (int r = 0; r < 4; ++r) {
        const long row = rowBase + wm * 64 + m * 16 + fk * 4 + r;
        float val = (float)acc[m][n][r] * alpha + bb;
        if (OM == 3) {
          H[row * N + col] += fqs(val, sO);
        } else {
          vmax = fmaxf(vmax, fabsf(val));
        }
      }
    }
  }
  if (OM == 1) {
    float m = warpMax(vmax);
    if ((tid & 63) == 0) red[tid >> 6] = m;
    __syncthreads();
    if (tid == 0) {
      float r = fmaxf(fmaxf(red[0], red[1]), fmaxf(red[2], red[3]));
      atomicMax(sc + slotO * 16 + ((blockIdx.x + blockIdx.y) & 15), __float_as_uint(r));
    }
  }
}

// ---------------------------------------------------------------------------
// k_vt: per (b,h), transpose V codes [400][64] -> VT8[bh][64][400] + colsumV.
// ---------------------------------------------------------------------------
__global__ __launch_bounds__(256) void k_vt(const signed char* __restrict__ qkv8,
                                            signed char* __restrict__ vt8,
                                            int* __restrict__ colsum) {
  __shared__ __align__(16) signed char T[64 * 80];
  __shared__ int cs[64];
  const int tid = threadIdx.x;
  const int bh = blockIdx.x, b = bh / 3, hh = bh % 3;
  const signed char* vb = qkv8 + (long)b * 400 * 576 + hh * 64 + 384;
  if (tid < 64) cs[tid] = 0;
  const int d = tid >> 2, seg = tid & 3;
  for (int c0 = 0; c0 < 448; c0 += 64) {
    __syncthreads();
    {
      int trow = tid >> 2, c = tid & 3;
      int4 v = make_int4(0, 0, 0, 0);
      if (c0 + trow < 400) v = *(const int4*)(vb + (long)(c0 + trow) * 576 + c * 16);
      *(int4*)&T[trow * 80 + c * 16] = v;
    }
    __syncthreads();
    int4 outw;
    int ssum = 0;
    u32 pk[4];
#pragma unroll
    for (int j = 0; j < 4; ++j) {
      u32 p = 0;
#pragma unroll
      for (int e = 0; e < 4; ++e) {
        int t = seg * 16 + j * 4 + e;
        int v = (int)T[t * 80 + d];
        ssum += v;
        p |= ((u32)(v & 0xff)) << (8 * e);
      }
      pk[j] = p;
    }
    outw.x = (int)pk[0]; outw.y = (int)pk[1]; outw.z = (int)pk[2]; outw.w = (int)pk[3];
    if (c0 + seg * 16 < 400)
      *(int4*)&vt8[(long)bh * 25600 + d * 400 + c0 + seg * 16] = outw;
    atomicAdd(&cs[d], ssum);
  }
  __syncthreads();
  if (tid < 64) colsum[bh * 64 + tid] = cs[tid];
}

// ---------------------------------------------------------------------------
// Attention, i8 MFMA, transposed scores. 1D grid 5376, XCD-chunked:
// vid = chunked(bid); bh = vid/7, tile = vid%7.
// Phase 0: global |score| absmax + per-row integer score max -> gmInt.
// ---------------------------------------------------------------------------
__device__ __forceinline__ void attn_swz(int& tile, int& bh) {
  int bid = blockIdx.x;
  int vid = (bid & 7) * ((int)gridDim.x >> 3) + (bid >> 3);
  tile = vid % 7;
  bh = vid / 7;
}

__global__ __launch_bounds__(256) void k_attn0(const signed char* __restrict__ qkv8,
                                               int* __restrict__ gmInt, u32* __restrict__ sc,
                                               int slotQ, int slotSc) {
  __shared__ __align__(16) signed char Qs[64 * 80];
  __shared__ __align__(16) signed char Ks[128 * 80];
  __shared__ float red[4];
  const int tid = threadIdx.x;
  int tile, bh;
  attn_swz(tile, bh);
  const int r0 = tile * 64;
  const int b = bh / 3, hh = bh % 3;
  const signed char* qb = qkv8 + (long)b * 400 * 576 + hh * 64;
  const signed char* kb = qb + 192;
  const float sQ = read_max16(sc, slotQ) / 127.0f + 1e-8f;
  const float sK = read_max16(sc, slotQ + 1) / 127.0f + 1e-8f;
  const float sSc = sQ * sK * 0.125f;

  {
    int row = tid >> 2, c = tid & 3;
    int4 v = make_int4(0, 0, 0, 0);
    if (r0 + row < 400) v = *(const int4*)(qb + (long)(r0 + row) * 576 + c * 16);
    *(int4*)&Qs[row * 80 + c * 16] = v;
  }
  const int lane = tid & 63, w = tid >> 6, fr = lane & 15, fk = lane >> 4;
  __syncthreads();
  int4v qf = *(const int4v*)&Qs[(16 * w + fr) * 80 + fk * 16];

  int aim = 0;
  int rim = -(1 << 30);
  for (int c0 = 0; c0 < 400; c0 += 128) {
    __syncthreads();
    {
      int trow = tid >> 1, half = tid & 1;
      int4 v0 = make_int4(0, 0, 0, 0), v1 = v0;
      if (c0 + trow < 400) {
        const signed char* kr = kb + (long)(c0 + trow) * 576 + half * 32;
        v0 = *(const int4*)kr;
        v1 = *(const int4*)(kr + 16);
      }
      *(int4*)&Ks[trow * 80 + half * 32] = v0;
      *(int4*)&Ks[trow * 80 + half * 32 + 16] = v1;
    }
    __syncthreads();
#pragma unroll
    for (int tf = 0; tf < 8; ++tf) {
      int4v kf = *(const int4v*)&Ks[(tf * 16 + fr) * 80 + fk * 16];
      int4v s = MFMA_I8(kf, qf, ((int4v){0, 0, 0, 0}));
      const bool tv = (c0 + tf * 16 + fk * 4) < 400;
#pragma unroll
      for (int r = 0; r < 4; ++r) {
        int sv = s[r];
        aim = max(aim, max(sv, -sv));
        if (tv) rim = max(rim, sv);
      }
    }
  }
  rim = max(rim, __shfl_xor(rim, 16));
  rim = max(rim, __shfl_xor(rim, 32));
  const int qloc = 16 * w + fr;
  const int gq = r0 + qloc;
  if (fk == 0 && gq < 400) gmInt[(long)bh * 400 + gq] = rim;
  float m = warpMax((float)aim * sSc);
  if (lane == 0) red[w] = m;
  __syncthreads();
  if (tid == 0) {
    float r = fmaxf(fmaxf(red[0], red[1]), fmaxf(red[2], red[3]));
    atomicMax(sc + slotSc * 16 + (blockIdx.x & 15), __float_as_uint(r));
  }
}

// Phase 1: flat exp2 sum with row max code from gmInt; gm <- code max (float), gl <- sum.
__global__ __launch_bounds__(256) void k_attn1(const signed char* __restrict__ qkv8,
                                               float* __restrict__ gm, float* __restrict__ gl,
                                               const int* __restrict__ gmInt,
                                               u32* __restrict__ sc, int slotQ, int slotSc,
                                               int slotPr) {
  __shared__ __align__(16) signed char Qs[64 * 80];
  __shared__ __align__(16) signed char Ks[128 * 80];
  __shared__ float red[4];
  const int tid = threadIdx.x;
  int tile, bh;
  attn_swz(tile, bh);
  const int r0 = tile * 64;
  const int b = bh / 3, hh = bh % 3;
  const signed char* qb = qkv8 + (long)b * 400 * 576 + hh * 64;
  const signed char* kb = qb + 192;
  const float sQ = read_max16(sc, slotQ) / 127.0f + 1e-8f;
  const float sK = read_max16(sc, slotQ + 1) / 127.0f + 1e-8f;
  const float sSc = sQ * sK * 0.125f;
  const float sS = read_max16(sc, slotSc) / 127.0f + 1e-8f;
  const float c1 = sSc / sS;
  const float c2 = sS * LOG2E;

  {
    int row = tid >> 2, c = tid & 3;
    int4 v = make_int4(0, 0, 0, 0);
    if (r0 + row < 400) v = *(const int4*)(qb + (long)(r0 + row) * 576 + c * 16);
    *(int4*)&Qs[row * 80 + c * 16] = v;
  }
  const int lane = tid & 63, w = tid >> 6, fr = lane & 15, fk = lane >> 4;
  __syncthreads();
  int4v qf = *(const int4v*)&Qs[(16 * w + fr) * 80 + fk * 16];

  const int qloc = 16 * w + fr;
  const int gq = r0 + qloc;
  const int gqc = (gq > 399) ? 399 : gq;
  const int mint = gmInt[(long)bh * 400 + gqc];
  const float cm = fminf(fmaxf(rintf((float)mint * c1), -128.f), 127.f);

  float sum = 0.f;
  for (int c0 = 0; c0 < 400; c0 += 128) {
    __syncthreads();
    {
      int trow = tid >> 1, half = tid & 1;
      int4 v0 = make_int4(0, 0, 0, 0), v1 = v0;
      if (c0 + trow < 400) {
        const signed char* kr = kb + (long)(c0 + trow) * 576 + half * 32;
        v0 = *(const int4*)kr;
        v1 = *(const int4*)(kr + 16);
      }
      *(int4*)&Ks[trow * 80 + half * 32] = v0;
      *(int4*)&Ks[trow * 80 + half * 32 + 16] = v1;
    }
    __syncthreads();
#pragma unroll
    for (int tf = 0; tf < 8; ++tf) {
      int4v kf = *(const int4v*)&Ks[(tf * 16 + fr) * 80 + fk * 16];
      int4v s = MFMA_I8(kf, qf, ((int4v){0, 0, 0, 0}));
      if ((c0 + tf * 16 + fk * 4) < 400) {
#pragma unroll
        for (int r = 0; r < 4; ++r) {
          float cf = fminf(fmaxf(rintf((float)s[r] * c1), -128.f), 127.f);
          sum += exp2f((cf - cm) * c2);
        }
      }
    }
  }
  sum += __shfl_xor(sum, 16);
  sum += __shfl_xor(sum, 32);
  float cand = 0.f;
  if (fk == 0 && gq < 400) {
    gm[(long)bh * 400 + gq] = cm;
    gl[(long)bh * 400 + gq] = sum;
    cand = 1.0f / sum;
  }
  float m = warpMax(cand);
  if (lane == 0) red[w] = m;
  __syncthreads();
  if (tid == 0) {
    float r = fmaxf(fmaxf(red[0], red[1]), fmaxf(red[2], red[3]));
    atomicMax(sc + slotPr * 16 + (blockIdx.x & 15), __float_as_uint(r));
  }
}

// Phase 2: probs -> (p-128) i8 codes -> out^T = VT·P'^T + 128*colsumV.
__global__ __launch_bounds__(256) void k_attn_pv(
    const signed char* __restrict__ qkv8, const signed char* __restrict__ vt8,
    const int* __restrict__ colsumV, float* __restrict__ ctx, const float* __restrict__ gm,
    const float* __restrict__ gl, u32* __restrict__ sc, int slotQ, int slotSc, int slotPr,
    int slotCtx) {
  __shared__ __align__(16) signed char Qs[64 * 80];
  __shared__ __align__(16) signed char Ks[128 * 80];
  __shared__ __align__(16) signed char Vs[64 * 144];
  __shared__ __align__(16) signed char Ps[64 * 144];
  __shared__ int colsV[64];
  __shared__ float red[4];
  const int tid = threadIdx.x;
  int tile, bh;
  attn_swz(tile, bh);
  const int r0 = tile * 64;
  const int b = bh / 3, hh = bh % 3;
  const signed char* qb = qkv8 + (long)b * 400 * 576 + hh * 64;
  const signed char* kb = qb + 192;
  const signed char* vtb = vt8 + (long)bh * 25600;
  const float sQ = read_max16(sc, slotQ) / 127.0f + 1e-8f;
  const float sK = read_max16(sc, slotQ + 1) / 127.0f + 1e-8f;
  const float sV = read_max16(sc, slotQ + 2) / 127.0f + 1e-8f;
  const float sSc = sQ * sK * 0.125f;
  const float sS = read_max16(sc, slotSc) / 127.0f + 1e-8f;
  const float sP = read_max16(sc, slotPr) / 255.0f + 1e-8f;
  const float sPV = sP * sV;
  const float c1 = sSc / sS;
  const float c2 = sS * LOG2E;

  {
    int row = tid >> 2, c = tid & 3;
    int4 v = make_int4(0, 0, 0, 0);
    if (r0 + row < 400) v = *(const int4*)(qb + (long)(r0 + row) * 576 + c * 16);
    *(int4*)&Qs[row * 80 + c * 16] = v;
  }
  if (tid < 64) colsV[tid] = colsumV[bh * 64 + tid];
  const int lane = tid & 63, w = tid >> 6, fr = lane & 15, fk = lane >> 4;
  __syncthreads();
  int4v qf = *(const int4v*)&Qs[(16 * w + fr) * 80 + fk * 16];

  const int qloc = 16 * w + fr;
  int gq = r0 + qloc;
  if (gq > 399) gq = 399;
  const float cm = gm[(long)bh * 400 + gq];
  const float invLsp = 1.0f / (gl[(long)bh * 400 + gq] * sP);

  int4v accd[4];
#pragma unroll
  for (int dt = 0; dt < 4; ++dt) accd[dt] = (int4v){0, 0, 0, 0};

  for (int c0 = 0; c0 < 400; c0 += 128) {
    __syncthreads();
    {  // K chunk
      int trow = tid >> 1, half = tid & 1;
      int4 v0 = make_int4(0, 0, 0, 0), v1 = v0;
      if (c0 + trow < 400) {
        const signed char* kr = kb + (long)(c0 + trow) * 576 + half * 32;
        v0 = *(const int4*)kr;
        v1 = *(const int4*)(kr + 16);
      }
      *(int4*)&Ks[trow * 80 + half * 32] = v0;
      *(int4*)&Ks[trow * 80 + half * 32 + 16] = v1;
    }
    {  // V^T chunk
      int d = tid >> 2, seg = tid & 3;
      int t0 = c0 + seg * 32;
      int4 u0 = make_int4(0, 0, 0, 0), u1 = u0;
      if (t0 < 400) u0 = *(const int4*)(vtb + d * 400 + t0);
      if (t0 + 16 < 400) u1 = *(const int4*)(vtb + d * 400 + t0 + 16);
      *(int4*)&Vs[d * 144 + seg * 32] = u0;
      *(int4*)&Vs[d * 144 + seg * 32 + 16] = u1;
    }
    __syncthreads();
#pragma unroll
    for (int tf = 0; tf < 8; ++tf) {
      int4v kf = *(const int4v*)&Ks[(tf * 16 + fr) * 80 + fk * 16];
      int4v s = MFMA_I8(kf, qf, ((int4v){0, 0, 0, 0}));
      const int tbase = c0 + tf * 16 + fk * 4;
      u32 pack = 0;
      if (tbase < 400) {
#pragma unroll
        for (int r = 0; r < 4; ++r) {
          float cf = fminf(fmaxf(rintf((float)s[r] * c1), -128.f), 127.f);
          float e = exp2f((cf - cm) * c2);
          float pu = fminf(fmaxf(rintf(e * invLsp), 0.f), 255.f);
          int pc = (int)pu - 128;
          pack |= ((u32)(pc & 0xff)) << (8 * r);
        }
      }
      *(u32*)&Ps[qloc * 144 + tf * 16 + fk * 4] = pack;
    }
    __syncthreads();
    int4v pf0 = *(const int4v*)&Ps[qloc * 144 + fk * 16];
    int4v pf1 = *(const int4v*)&Ps[qloc * 144 + 64 + fk * 16];
#pragma unroll
    for (int dt = 0; dt < 4; ++dt) {
      int4v vf0 = *(const int4v*)&Vs[(dt * 16 + fr) * 144 + fk * 16];
      int4v vf1 = *(const int4v*)&Vs[(dt * 16 + fr) * 144 + 64 + fk * 16];
      accd[dt] = MFMA_I8(vf0, pf0, accd[dt]);
      accd[dt] = MFMA_I8(vf1, pf1, accd[dt]);
    }
  }
  float vmax = 0.f;
  const int q = r0 + qloc;
  if (q < 400) {
#pragma unroll
    for (int dt = 0; dt < 4; ++dt) {
      const int d0 = dt * 16 + fk * 4;
      float4 o;
      o.x = sPV * (float)(accd[dt][0] + 128 * colsV[d0 + 0]);
      o.y = sPV * (float)(accd[dt][1] + 128 * colsV[d0 + 1]);
      o.z = sPV * (float)(accd[dt][2] + 128 * colsV[d0 + 2]);
      o.w = sPV * (float)(accd[dt][3] + 128 * colsV[d0 + 3]);
      vmax = fmaxf(vmax, fmaxf(fmaxf(fabsf(o.x), fabsf(o.y)), fmaxf(fabsf(o.z), fabsf(o.w))));
      *(float4*)&ctx[(long)(b * 400 + q) * 192 + hh * 64 + d0] = o;
    }
  }
  float m = warpMax(vmax);
  if (lane == 0) red[w] = m;
  __syncthreads();
  if (tid == 0) {
    float r = fmaxf(fmaxf(red[0], red[1]), fmaxf(red[2], red[3]));
    atomicMax(sc + slotCtx * 16 + (blockIdx.x & 15), __float_as_uint(r));
  }
}

// ---------------------------------------------------------------------------
// final pool + logits
// ---------------------------------------------------------------------------
__global__ __launch_bounds__(192) void k_pool(const float* __restrict__ xln,
                                              float* __restrict__ pooled,
                                              u32* __restrict__ slot) {
  int b = blockIdx.x, d = threadIdx.x;
  float sum = 0.f;
  for (int s = 0; s < 400; ++s) sum += xln[((long)b * 400 + s) * 192 + d];
  float v = sum / 400.0f;
  pooled[(long)b * 192 + d] = v;
  __shared__ float red[3];
  float m = warpMax(fabsf(v));
  if ((d & 63) == 0) red[d >> 6] = m;
  __syncthreads();
  if (d == 0)
    atomicMax(slot + (b & 15), __float_as_uint(fmaxf(fmaxf(red[0], red[1]), red[2])));
}

__global__ __launch_bounds__(64) void k_logits(const float* __restrict__ pooled,
                                               const float* __restrict__ clfq,
                                               const float* __restrict__ clfb,
                                               const u32* __restrict__ sc,
                                               float* __restrict__ out) {
  int c = blockIdx.x, b = blockIdx.y, lane = threadIdx.x;
  float sp = read_max16(sc, SLOT_POOL) / 127.0f + 1e-8f;
  float acc = 0.f;
#pragma unroll
  for (int j = 0; j < 3; ++j) {
    int d = lane + 64 * j;
    acc += fqs(pooled[(long)b * 192 + d], sp) * clfq[c * 192 + d];
  }
#pragma unroll
  for (int o = 32; o > 0; o >>= 1) acc += __shfl_down(acc, o);
  if (lane == 0) out[b * 7 + c] = acc + clfb[c];
}

// ---------------------------------------------------------------------------
// host
// ---------------------------------------------------------------------------
static inline int gsz(long n4, long cap) {
  long g = (n4 + 255) / 256;
  return (int)(g < cap ? g : cap);
}

extern "C" void kernel_launch(void* const* d_in, const int* in_sizes, int n_in,
                              void* d_out, int out_size, void* d_ws, size_t ws_size,
                              hipStream_t stream) {
  (void)in_sizes; (void)n_in; (void)out_size; (void)ws_size;

  const float* x = (const float*)d_in[0];
  const float* pw = (const float*)d_in[1];
  const float* pb = (const float*)d_in[2];
  const float* ln1g = (const float*)d_in[3];
  const float* ln1b = (const float*)d_in[4];
  const float* wqkv = (const float*)d_in[5];
  const float* bqkv = (const float*)d_in[6];
  const float* wo = (const float*)d_in[7];
  const float* bo = (const float*)d_in[8];
  const float* ln2g = (const float*)d_in[9];
  const float* ln2b = (const float*)d_in[10];
  const float* w1 = (const float*)d_in[11];
  const float* b1 = (const float*)d_in[12];
  const float* w2 = (const float*)d_in[13];
  const float* b2 = (const float*)d_in[14];
  const float* lnfg = (const float*)d_in[15];
  const float* lnfb = (const float*)d_in[16];
  const float* clfw = (const float*)d_in[17];
  const float* clfb = (const float*)d_in[18];

  float* ws = (float*)d_ws;
  u32* sc = (u32*)d_ws;
  float* GM = ws + OFF_GM;
  int* GMI = (int*)GM;
  float* GL = ws + OFF_GL;
  float* POOL = ws + OFF_POOL;
  float* PWQ = ws + OFF_PWQ;
  float* CLFQ = ws + OFF_CLFQ;
  float* H = ws + OFF_H;
  float* Af = ws + OFF_A;
  u16* XH = (u16*)(ws + OFF_A);
  u16* XL = XH + 19660800;
  signed char* U8 = (signed char*)(ws + OFF_U);
  signed char* VT8 = U8 + 58982400;
  int* COLSUM = (int*)POOL;
  signed char* WQC = (signed char*)POOL;
  signed char* WOC = (signed char*)GL;  // GL free during wo/w1/w2 quant? NO — GL live.
  // keep weight scratch in GM-adjacent free space: use POOL tail for wo/w1/w2.
  // POOL region = 49152 floats = 196,608 B; WQC uses 110,592 B. Place wo/w1/w2
  // codes in the U8 tail beyond qkv+VT8? U8 region exactly full. Use GM region:
  // GM holds gmInt (1,228,800 B region); only first 307,200*4 B... GM region is
  // 307200 floats = 1,228,800 B; gmInt uses 768*400*4 = 1,228,800 B. Full.
  // GL region: 1,228,800 B; gl uses full too. So reuse POOL for WQC (wo fits:
  // 36,864 B after WQC's last use) and W1C/W2C in Af region tail (free during
  // MLP weight quant: planes occupy XH/XL = full A region... planes ARE the A
  // region. BUT W1C is consumed while planes live -> need separate space.
  // Simplest: pack wo/w1/w2 codes into POOL sequentially: 36,864+147,456 =
  // 184,320 <= 196,608 B for wo+w1; w2 goes to WQC slot (110,592 B: w2 needs
  // 147,456 B -> doesn't fit). Solution: quantize w2 into POOL after w1's last
  // use (w1 gemm done before w2 gemm).
  float* out = (float*)d_out;

  signed char* WOC2 = (signed char*)POOL;                // 36,864 B   (wo)
  signed char* W1C2 = (signed char*)POOL + 36864;        // 147,456 B  (w1)
  signed char* W2C2 = (signed char*)POOL + 36864;        // w2 overwrites w1 slot later

  k_zero<<<(N_SLOT_WORDS + 255) / 256, 256, 0, stream>>>(sc, N_SLOT_WORDS);

  auto amax = [&](const float* p, long n, int slot) {
    k_absmax<<<gsz(n / 4, 256), 256, 0, stream>>>((const float4*)p, n / 4, sc + slot * 16);
  };
  amax(pw, 3840, SLOT_PW);
  amax(clfw, 1344, SLOT_CLF);
  amax(x, 2048000, SLOT_X);
  for (int i = 0; i < NL; ++i) {
    int Lb = 16 + i * 16;
    amax(wqkv + (long)i * 110592, 110592, Lb + 0);
    amax(wo + (long)i * 36864, 36864, Lb + 1);
    amax(w1 + (long)i * 147456, 147456, Lb + 2);
    amax(w2 + (long)i * 147456, 147456, Lb + 3);
  }
  k_quant4<<<gsz(960, 256), 256, 0, stream>>>((const float4*)pw, (float4*)PWQ, 960, sc, SLOT_PW);
  k_quant4<<<gsz(336, 256), 256, 0, stream>>>((const float4*)clfw, (float4*)CLFQ, 336, sc,
                                              SLOT_CLF);

  // patch embed -> Af -> quant into H; first LN -> planes
  k_patch<<<12800, 192, 0, stream>>>(x, PWQ, pb, sc, Af, sc + SLOT_EMB * 16);
  k_quant4<<<2048, 256, 0, stream>>>((const float4*)Af, (float4*)H, 19660800 / 4, sc, SLOT_EMB);
  k_ln<true><<<(int)(ROWS / 4), 256, 0, stream>>>(H, ln1g, ln1b, XH, XL, nullptr, (int)ROWS);

  for (int i = 0; i < NL; ++i) {
    int Lb = 16 + i * 16;
    // --- attention ---
    k_wquant<<<108, 256, 0, stream>>>((const float4*)(wqkv + (long)i * 110592), (u32*)WQC,
                                      27648, sc, Lb + 0);
    k_gemmA<false, 1><<<2400, 256, 0, stream>>>(XH, XL, WQC, Lb + 0, bqkv + i * 576, nullptr,
                                                576, 192, 3, sc, Lb + 4, 192);
    k_gemmA<false, 2><<<2400, 256, 0, stream>>>(XH, XL, WQC, Lb + 0, bqkv + i * 576, U8, 576,
                                                192, 3, sc, Lb + 4, 192);
    k_vt<<<768, 256, 0, stream>>>(U8, VT8, COLSUM);
    k_attn0<<<5376, 256, 0, stream>>>(U8, GMI, sc, Lb + 4, Lb + 7);
    k_attn1<<<5376, 256, 0, stream>>>(U8, GM, GL, GMI, sc, Lb + 4, Lb + 7, Lb + 8);
    k_attn_pv<<<5376, 256, 0, stream>>>(U8, VT8, COLSUM, Af, GM, GL, sc, Lb + 4, Lb + 7,
                                        Lb + 8, Lb + 9);
    // ctx fp32 (Af) -> int8 codes (U8 head); wo/w1 weight codes into POOL
    k_quant_codes<<<2048, 256, 0, stream>>>((const float4*)Af, (u32*)U8, 19660800 / 4, sc,
                                            Lb + 9);
    k_wquant<<<36, 256, 0, stream>>>((const float4*)(wo + (long)i * 36864), (u32*)WOC2, 9216,
                                     sc, Lb + 1);
    {
      dim3 g(1, 800);
      k_gemm8<1><<<g, 256, 0, stream>>>(U8, Lb + 9, WOC2, Lb + 1, bo + i * 192, nullptr, 192,
                                        192, sc, Lb + 10);
      k_gemm8<3><<<g, 256, 0, stream>>>(U8, Lb + 9, WOC2, Lb + 1, bo + i * 192, H, 192, 192,
                                        sc, Lb + 10);
    }
    // LN2 -> planes
    k_ln<true><<<(int)(ROWS / 4), 256, 0, stream>>>(H, ln2g + i * 192, ln2b + i * 192, XH, XL,
                                                    nullptr, (int)ROWS);
    // --- MLP ---
    k_wquant<<<144, 256, 0, stream>>>((const float4*)(w1 + (long)i * 147456), (u32*)W1C2,
                                      36864, sc, Lb + 2);
    k_gemmA<true, 1><<<3200, 256, 0, stream>>>(XH, XL, W1C2, Lb + 2, b1 + i * 768, nullptr,
                                               768, 192, 4, sc, Lb + 11, 768);
    k_gemmA<true, 2><<<3200, 256, 0, stream>>>(XH, XL, W1C2, Lb + 2, b1 + i * 768, U8, 768,
                                               192, 4, sc, Lb + 11, 768);
    k_wquant<<<144, 256, 0, stream>>>((const float4*)(w2 + (long)i * 147456), (u32*)W2C2,
                                      36864, sc, Lb + 3);
    {
      dim3 g(1, 800);
      k_gemm8<1><<<g, 256, 0, stream>>>(U8, Lb + 11, W2C2, Lb + 3, b2 + i * 192, nullptr, 192,
                                        768, sc, Lb + 12);
      k_gemm8<3><<<g, 256, 0, stream>>>(U8, Lb + 11, W2C2, Lb + 3, b2 + i * 192, H, 192, 768,
                                        sc, Lb + 12);
    }
    if (i < NL - 1) {
      k_ln<true><<<(int)(ROWS / 4), 256, 0, stream>>>(H, ln1g + (i + 1) * 192,
                                                      ln1b + (i + 1) * 192, XH, XL, nullptr,
                                                      (int)ROWS);
    } else {
      k_ln<false><<<(int)(ROWS / 4), 256, 0, stream>>>(H, lnfg, lnfb, nullptr, nullptr, Af,
                                                       (int)ROWS);
    }
  }

  // pool + classifier (POOL region free again: weight codes dead)
  k_pool<<<256, 192, 0, stream>>>(Af, POOL, sc + SLOT_POOL * 16);
  {
    dim3 g(7, 256);
    k_logits<<<g, 64, 0, stream>>>(POOL, CLFQ, clfb, sc, out);
  }
}

// Round 8
// 7769.868 us; speedup vs baseline: 1.5093x; 1.0580x over previous
//
#include <hip/hip_runtime.h>
#include <math.h>

// ---------------------------------------------------------------------------
// TinyMyo 8ch/400tok quant transformer — v8: all-int8 MFMA GEMMs.
// LN output -> per-row i16 codes (2x i8 planes); GEMM = 256*(hi·W) + lo·W via
// mfma_i32_16x16x64_i8 (exact). Attention as v7 (exp2 softmax, XCD swizzle).
// ---------------------------------------------------------------------------

typedef unsigned int u32;
typedef unsigned short u16;
typedef __attribute__((ext_vector_type(4))) int int4v;

#define MFMA_I8(a, b, c) __builtin_amdgcn_mfma_i32_16x16x64_i8((a), (b), (c), 0, 0, 0)

constexpr int NL = 8;
constexpr long ROWS = 102400;  // B*SEQ
constexpr float LOG2E = 1.44269504088896340736f;

// ---- scale slots (each 16 shadow u32 words) ----
constexpr int SLOT_X = 0, SLOT_PW = 1, SLOT_EMB = 2, SLOT_CLF = 3, SLOT_POOL = 4;
constexpr int N_SLOT_WORDS = 200 * 16;

// ---- ws layout (float units) ----
constexpr long OFF_GM = 3200;
constexpr long OFF_GL = OFF_GM + 307200;
constexpr long OFF_POOL = OFF_GL + 307200;
constexpr long OFF_PWQ = OFF_POOL + 49152;
constexpr long OFF_CLFQ = OFF_PWQ + 3840;
constexpr long OFF_H = OFF_CLFQ + 1344;
constexpr long OFF_A = OFF_H + 19660800;
constexpr long OFF_U = OFF_A + 19660800;

// ---------------------------------------------------------------------------
// helpers
// ---------------------------------------------------------------------------
__device__ __forceinline__ float warpMax(float v) {
#pragma unroll
  for (int o = 32; o > 0; o >>= 1) v = fmaxf(v, __shfl_down(v, o));
  return v;
}

__device__ __forceinline__ float read_max16(const u32* sc, int slot) {
  const u32* p = sc + slot * 16;
  u32 m = 0;
#pragma unroll
  for (int i = 0; i < 16; ++i) m = max(m, p[i]);
  return __uint_as_float(m);
}

__device__ __forceinline__ float fqs(float x, float s) {
  return fminf(fmaxf(rintf(x / s), -128.0f), 127.0f) * s;
}

// ---------------------------------------------------------------------------
// small utility kernels
// ---------------------------------------------------------------------------
__global__ void k_zero(u32* p, int n) {
  int i = blockIdx.x * blockDim.x + threadIdx.x;
  if (i < n) p[i] = 0u;
}

__global__ __launch_bounds__(256) void k_absmax(const float4* __restrict__ x, long n4,
                                                u32* __restrict__ slot) {
  float m = 0.f;
  for (long i = (long)blockIdx.x * blockDim.x + threadIdx.x; i < n4;
       i += (long)gridDim.x * blockDim.x) {
    float4 v = x[i];
    m = fmaxf(m, fmaxf(fmaxf(fabsf(v.x), fabsf(v.y)), fmaxf(fabsf(v.z), fabsf(v.w))));
  }
  __shared__ float red[4];
  m = warpMax(m);
  int lane = threadIdx.x & 63, w = threadIdx.x >> 6;
  if (lane == 0) red[w] = m;
  __syncthreads();
  if (threadIdx.x == 0) {
    float r = fmaxf(fmaxf(red[0], red[1]), fmaxf(red[2], red[3]));
    atomicMax(slot + (blockIdx.x & 15), __float_as_uint(r));
  }
}

__global__ __launch_bounds__(256) void k_quant4(const float4* __restrict__ in,
                                                float4* __restrict__ out, long n4,
                                                const u32* __restrict__ sc, int slot) {
  float s = read_max16(sc, slot) / 127.0f + 1e-8f;
  for (long i = (long)blockIdx.x * blockDim.x + threadIdx.x; i < n4;
       i += (long)gridDim.x * blockDim.x) {
    float4 v = in[i];
    v.x = fqs(v.x, s); v.y = fqs(v.y, s); v.z = fqs(v.z, s); v.w = fqs(v.w, s);
    out[i] = v;
  }
}

__global__ __launch_bounds__(256) void k_quant_codes(const float4* __restrict__ in,
                                                     u32* __restrict__ out, long n4,
                                                     const u32* __restrict__ sc, int slot) {
  float s = read_max16(sc, slot) / 127.0f + 1e-8f;
  for (long i = (long)blockIdx.x * blockDim.x + threadIdx.x; i < n4;
       i += (long)gridDim.x * blockDim.x) {
    float4 v = in[i];
    int c0 = (int)fminf(fmaxf(rintf(v.x / s), -128.f), 127.f);
    int c1 = (int)fminf(fmaxf(rintf(v.y / s), -128.f), 127.f);
    int c2 = (int)fminf(fmaxf(rintf(v.z / s), -128.f), 127.f);
    int c3 = (int)fminf(fmaxf(rintf(v.w / s), -128.f), 127.f);
    out[i] = (u32)(c0 & 0xff) | ((u32)(c1 & 0xff) << 8) | ((u32)(c2 & 0xff) << 16) |
             ((u32)(c3 & 0xff) << 24);
  }
}

// ---------------------------------------------------------------------------
// patch embed
// ---------------------------------------------------------------------------
__global__ __launch_bounds__(192) void k_patch(const float* __restrict__ x,
                                               const float* __restrict__ pwq,
                                               const float* __restrict__ pb,
                                               const u32* __restrict__ sc,
                                               float* __restrict__ emb,
                                               u32* __restrict__ embSlot) {
  __shared__ float xq[8][20];
  __shared__ float red[3];
  const int tid = threadIdx.x;
  const long rowBase = (long)blockIdx.x * 8;
  const float sx = read_max16(sc, SLOT_X) / 127.0f + 1e-8f;
  if (tid < 160) {
    int r = tid / 20, k = tid % 20;
    xq[r][k] = fqs(x[(rowBase + r) * 20 + k], sx);
  }
  __syncthreads();
  float wreg[20];
#pragma unroll
  for (int k = 0; k < 20; ++k) wreg[k] = pwq[tid * 20 + k];
  const float bias = pb[tid];
  float m = 0.f;
  for (int r = 0; r < 8; ++r) {
    float acc = bias;
#pragma unroll
    for (int k = 0; k < 20; ++k) acc += xq[r][k] * wreg[k];
    emb[(rowBase + r) * 192 + tid] = acc;
    m = fmaxf(m, fabsf(acc));
  }
  m = warpMax(m);
  if ((tid & 63) == 0) red[tid >> 6] = m;
  __syncthreads();
  if (tid == 0)
    atomicMax(embSlot + (blockIdx.x & 15),
              __float_as_uint(fmaxf(fmaxf(red[0], red[1]), red[2])));
}

// ---------------------------------------------------------------------------
// LayerNorm (reads only H).
// I16: emit per-row-scaled i16 codes as hi/lo i8 planes + row scale.
// else: fp32 out.
// ---------------------------------------------------------------------------
template <bool I16>
__global__ __launch_bounds__(256) void k_ln(const float* __restrict__ x,
                                            const float* __restrict__ g,
                                            const float* __restrict__ bta,
                                            signed char* __restrict__ yh,
                                            signed char* __restrict__ yl,
                                            float* __restrict__ sArow,
                                            float* __restrict__ yf, int rows) {
  int w = threadIdx.x >> 6, lane = threadIdx.x & 63;
  long row = (long)blockIdx.x * 4 + w;
  if (row >= rows) return;
  const float* xr = x + row * 192;
  float v0 = xr[lane], v1 = xr[lane + 64], v2 = xr[lane + 128];
  float s = v0 + v1 + v2;
#pragma unroll
  for (int o = 32; o > 0; o >>= 1) s += __shfl_down(s, o);
  s = __shfl(s, 0);
  float mean = s / 192.0f;
  float d0 = v0 - mean, d1 = v1 - mean, d2 = v2 - mean;
  float q = d0 * d0 + d1 * d1 + d2 * d2;
#pragma unroll
  for (int o = 32; o > 0; o >>= 1) q += __shfl_down(q, o);
  q = __shfl(q, 0);
  float rs = 1.0f / sqrtf(q / 192.0f + 1e-5f);
  float o0 = d0 * rs * g[lane] + bta[lane];
  float o1 = d1 * rs * g[lane + 64] + bta[lane + 64];
  float o2 = d2 * rs * g[lane + 128] + bta[lane + 128];
  if (I16) {
    float rm = fmaxf(fabsf(o0), fmaxf(fabsf(o1), fabsf(o2)));
#pragma unroll
    for (int o = 32; o > 0; o >>= 1) rm = fmaxf(rm, __shfl_down(rm, o));
    rm = __shfl(rm, 0);
    float sA = rm / 32512.0f + 1e-20f;
    float inv = 1.0f / sA;
    long b = row * 192;
    int c0 = (int)rintf(o0 * inv);
    int c1 = (int)rintf(o1 * inv);
    int c2 = (int)rintf(o2 * inv);
    int h0 = (c0 + 128) >> 8, h1 = (c1 + 128) >> 8, h2 = (c2 + 128) >> 8;
    yh[b + lane] = (signed char)h0;        yl[b + lane] = (signed char)(c0 - (h0 << 8));
    yh[b + lane + 64] = (signed char)h1;   yl[b + lane + 64] = (signed char)(c1 - (h1 << 8));
    yh[b + lane + 128] = (signed char)h2;  yl[b + lane + 128] = (signed char)(c2 - (h2 << 8));
    if (lane == 0) sArow[row] = sA;
  } else {
    float* yr = yf + row * 192;
    yr[lane] = o0; yr[lane + 64] = o1; yr[lane + 128] = o2;
  }
}

// ---------------------------------------------------------------------------
// weight fp32 -> int8 codes
// ---------------------------------------------------------------------------
__global__ __launch_bounds__(256) void k_wquant(const float4* __restrict__ w,
                                                u32* __restrict__ out, int n4,
                                                const u32* __restrict__ sc, int slot) {
  int i = blockIdx.x * blockDim.x + threadIdx.x;
  if (i >= n4) return;
  float s = read_max16(sc, slot) / 127.0f + 1e-8f;
  float4 v = w[i];
  int c0 = (int)fminf(fmaxf(rintf(v.x / s), -128.f), 127.f);
  int c1 = (int)fminf(fmaxf(rintf(v.y / s), -128.f), 127.f);
  int c2 = (int)fminf(fmaxf(rintf(v.z / s), -128.f), 127.f);
  int c3 = (int)fminf(fmaxf(rintf(v.w / s), -128.f), 127.f);
  out[i] = (u32)(c0 & 0xff) | ((u32)(c1 & 0xff) << 8) | ((u32)(c2 & 0xff) << 16) |
           ((u32)(c3 & 0xff) << 24);
}

// ---------------------------------------------------------------------------
// i16-A (hi/lo i8 planes) x i8-W GEMM, exact integer accumulation.
// C[M,N] = sArow[row]*sW*(256*(AH·W) + AL·W) + bias [,gelu].
// OM 1: absmax only; OM 2: int8 code store.
// BM=128 BN=96 BK=64, K=192 fixed. 4 waves (2m x 2n); wave = 4m x 3n frags.
// 1D grid, XCD-chunked, col-fastest: bx = vid % ncol.
// ---------------------------------------------------------------------------
template <bool GELU, int OM>
__global__ __launch_bounds__(256) void k_gemm16(
    const signed char* __restrict__ AH, const signed char* __restrict__ AL,
    const float* __restrict__ sArow, const signed char* __restrict__ W8, int slotW,
    const float* __restrict__ bias, signed char* __restrict__ C8, int N, int ncol,
    u32* __restrict__ sc, int slotO, int colsPerSlot) {
  __shared__ __align__(16) signed char Ah[128 * 80];
  __shared__ __align__(16) signed char Al[128 * 80];
  __shared__ __align__(16) signed char Bs[96 * 80];
  __shared__ float sAs[128];
  __shared__ float red[4];
  const int tid = threadIdx.x;
  const int bid = blockIdx.x;
  const int vid = (bid & 7) * ((int)gridDim.x >> 3) + (bid >> 3);
  const int bx = vid % ncol;
  const long by = vid / ncol;
  const long rowBase = by * 128;
  const int colBase = bx * 96;
  const float sW = read_max16(sc, slotW) / 127.0f + 1e-8f;

  if (tid < 128) sAs[tid] = sArow[rowBase + tid];

  const int lane = tid & 63, wv = tid >> 6;
  const int wm = wv >> 1, wn = wv & 1;
  const int fr = lane & 15, fk = lane >> 4;

  int4v accH[4][3], accL[4][3];
#pragma unroll
  for (int m = 0; m < 4; ++m)
#pragma unroll
    for (int n = 0; n < 3; ++n) {
      accH[m][n] = (int4v){0, 0, 0, 0};
      accL[m][n] = (int4v){0, 0, 0, 0};
    }

  const int arow = tid >> 1, ahalf = tid & 1;

  for (int k0 = 0; k0 < 192; k0 += 64) {
    {
      const long ga = (rowBase + arow) * 192 + k0 + ahalf * 32;
      *(int4*)&Ah[arow * 80 + ahalf * 32] = *(const int4*)(AH + ga);
      *(int4*)&Ah[arow * 80 + ahalf * 32 + 16] = *(const int4*)(AH + ga + 16);
      *(int4*)&Al[arow * 80 + ahalf * 32] = *(const int4*)(AL + ga);
      *(int4*)&Al[arow * 80 + ahalf * 32 + 16] = *(const int4*)(AL + ga + 16);
    }
    if (tid < 192) {
      const long gb = (long)(colBase + (tid >> 1)) * 192 + k0 + (tid & 1) * 32;
      *(int4*)&Bs[(tid >> 1) * 80 + (tid & 1) * 32] = *(const int4*)(W8 + gb);
      *(int4*)&Bs[(tid >> 1) * 80 + (tid & 1) * 32 + 16] = *(const int4*)(W8 + gb + 16);
    }
    __syncthreads();
    int4v bfr[3];
#pragma unroll
    for (int n = 0; n < 3; ++n)
      bfr[n] = *(const int4v*)&Bs[(wn * 48 + n * 16 + fr) * 80 + fk * 16];
#pragma unroll
    for (int m = 0; m < 4; ++m) {
      int4v ah = *(const int4v*)&Ah[(wm * 64 + m * 16 + fr) * 80 + fk * 16];
      int4v al = *(const int4v*)&Al[(wm * 64 + m * 16 + fr) * 80 + fk * 16];
#pragma unroll
      for (int n = 0; n < 3; ++n) {
        accH[m][n] = MFMA_I8(ah, bfr[n], accH[m][n]);
        accL[m][n] = MFMA_I8(al, bfr[n], accL[m][n]);
      }
    }
    __syncthreads();
  }

  float sOinv = 0.f;
  if (OM == 2) sOinv = 1.0f / (read_max16(sc, slotO + colBase / colsPerSlot) / 127.0f + 1e-8f);
  const float inv_sqrt2 = 0.70710678118654752440f;
  float vmax = 0.f;
#pragma unroll
  for (int n = 0; n < 3; ++n) {
    const int col = colBase + wn * 48 + n * 16 + fr;
    const float bb = bias[col];
#pragma unroll
    for (int m = 0; m < 4; ++m) {
      const int ri = wm * 64 + m * 16 + fk * 4;
#pragma unroll
      for (int r = 0; r < 4; ++r) {
        const float sA = sAs[ri + r];
        const int R = (accH[m][n][r] << 8) + accL[m][n][r];
        float val = (float)R * (sA * sW) + bb;
        if (GELU) val = 0.5f * val * (1.0f + erff(val * inv_sqrt2));
        if (OM == 2) {
          float code = fminf(fmaxf(rintf(val * sOinv), -128.f), 127.f);
          C8[(rowBase + ri + r) * N + col] = (signed char)code;
        } else {
          vmax = fmaxf(vmax, fabsf(val));
        }
      }
    }
  }
  if (OM == 1) {
    float m = warpMax(vmax);
    if ((tid & 63) == 0) red[tid >> 6] = m;
    __syncthreads();
    if (tid == 0) {
      float r = fmaxf(fmaxf(red[0], red[1]), fmaxf(red[2], red[3]));
      atomicMax(sc + (slotO + colBase / colsPerSlot) * 16 + ((int)(bx + by) & 15),
                __float_as_uint(r));
    }
  }
}

// ---------------------------------------------------------------------------
// i8-MFMA GEMM (A = int8 codes). OM 1: absmax; OM 3: H += fq(val, sO).
// BM=128 BN=192 BK=64.
// ---------------------------------------------------------------------------
template <int OM>
__global__ __launch_bounds__(256) void k_gemm8(
    const signed char* __restrict__ A8, int slotA, const signed char* __restrict__ W8,
    int slotW, const float* __restrict__ bias, float* __restrict__ H, int N, int K,
    u32* __restrict__ sc, int slotO) {
  __shared__ __align__(16) signed char As[128 * 80];
  __shared__ __align__(16) signed char Bs[192 * 80];
  __shared__ float red[4];
  const int tid = threadIdx.x;
  const long rowBase = (long)blockIdx.y * 128;
  const int colBase = blockIdx.x * 192;
  const float alpha = (read_max16(sc, slotA) / 127.0f + 1e-8f) *
                      (read_max16(sc, slotW) / 127.0f + 1e-8f);

  const int lane = tid & 63, wv = tid >> 6;
  const int wm = wv >> 1, wn = wv & 1;
  const int fr = lane & 15, fk = lane >> 4;

  int4v acc[4][6];
#pragma unroll
  for (int m = 0; m < 4; ++m)
#pragma unroll
    for (int n = 0; n < 6; ++n) acc[m][n] = (int4v){0, 0, 0, 0};

  const int arow = tid >> 1, ahalf = tid & 1;

  for (int k0 = 0; k0 < K; k0 += 64) {
    {
      const signed char* ap = A8 + (rowBase + arow) * (long)K + k0 + ahalf * 32;
      *(int4*)&As[arow * 80 + ahalf * 32] = *(const int4*)ap;
      *(int4*)&As[arow * 80 + ahalf * 32 + 16] = *(const int4*)(ap + 16);
    }
    if (tid < 192) {
      const signed char* wp = W8 + (long)(colBase + tid) * K + k0;
#pragma unroll
      for (int j = 0; j < 4; ++j)
        *(int4*)&Bs[tid * 80 + j * 16] = *(const int4*)(wp + j * 16);
    }
    __syncthreads();
    int4v bfr[6];
#pragma unroll
    for (int n = 0; n < 6; ++n)
      bfr[n] = *(const int4v*)&Bs[(wn * 96 + n * 16 + fr) * 80 + fk * 16];
#pragma unroll
    for (int m = 0; m < 4; ++m) {
      int4v af = *(const int4v*)&As[(wm * 64 + m * 16 + fr) * 80 + fk * 16];
#pragma unroll
      for (int n = 0; n < 6; ++n) acc[m][n] = MFMA_I8(af, bfr[n], acc[m][n]);
    }
    __syncthreads();
  }

  float sO = 1.f;
  if (OM == 3) sO = read_max16(sc, slotO) / 127.0f + 1e-8f;
  float vmax = 0.f;
#pragma unroll
  for (int n = 0; n < 6; ++n) {
    const int col = colBase + wn * 96 + n * 16 + fr;
    const float bb = bias[col];
#pragma unroll
    for (int m = 0; m < 4; ++m) {
#pragma unroll
      for (int r = 0; r < 4; ++r) {
        const long row = rowBase + wm * 64 + m * 16 + fk * 4 + r;
        float val = (float)acc[m][n][r] * alpha + bb;
        if (OM == 3) {
          H[row * N + col] += fqs(val, sO);
        } else {
          vmax = fmaxf(vmax, fabsf(val));
        }
      }
    }
  }
  if (OM == 1) {
    float m = warpMax(vmax);
    if ((tid & 63) == 0) red[tid >> 6] = m;
    __syncthreads();
    if (tid == 0) {
      float r = fmaxf(fmaxf(red[0], red[1]), fmaxf(red[2], red[3]));
      atomicMax(sc + slotO * 16 + ((blockIdx.x + blockIdx.y) & 15), __float_as_uint(r));
    }
  }
}

// ---------------------------------------------------------------------------
// k_vt: per (b,h), transpose V codes [400][64] -> VT8[bh][64][400] + colsumV.
// ---------------------------------------------------------------------------
__global__ __launch_bounds__(256) void k_vt(const signed char* __restrict__ qkv8,
                                            signed char* __restrict__ vt8,
                                            int* __restrict__ colsum) {
  __shared__ __align__(16) signed char T[64 * 80];
  __shared__ int cs[64];
  const int tid = threadIdx.x;
  const int bh = blockIdx.x, b = bh / 3, hh = bh % 3;
  const signed char* vb = qkv8 + (long)b * 400 * 576 + hh * 64 + 384;
  if (tid < 64) cs[tid] = 0;
  const int d = tid >> 2, seg = tid & 3;
  for (int c0 = 0; c0 < 448; c0 += 64) {
    __syncthreads();
    {
      int trow = tid >> 2, c = tid & 3;
      int4 v = make_int4(0, 0, 0, 0);
      if (c0 + trow < 400) v = *(const int4*)(vb + (long)(c0 + trow) * 576 + c * 16);
      *(int4*)&T[trow * 80 + c * 16] = v;
    }
    __syncthreads();
    int4 outw;
    int ssum = 0;
    u32 pk[4];
#pragma unroll
    for (int j = 0; j < 4; ++j) {
      u32 p = 0;
#pragma unroll
      for (int e = 0; e < 4; ++e) {
        int t = seg * 16 + j * 4 + e;
        int v = (int)T[t * 80 + d];
        ssum += v;
        p |= ((u32)(v & 0xff)) << (8 * e);
      }
      pk[j] = p;
    }
    outw.x = (int)pk[0]; outw.y = (int)pk[1]; outw.z = (int)pk[2]; outw.w = (int)pk[3];
    if (c0 + seg * 16 < 400)
      *(int4*)&vt8[(long)bh * 25600 + d * 400 + c0 + seg * 16] = outw;
    atomicAdd(&cs[d], ssum);
  }
  __syncthreads();
  if (tid < 64) colsum[bh * 64 + tid] = cs[tid];
}

// ---------------------------------------------------------------------------
// Attention, i8 MFMA, transposed scores. 1D grid 5376, XCD-chunked.
// ---------------------------------------------------------------------------
__device__ __forceinline__ void attn_swz(int& tile, int& bh) {
  int bid = blockIdx.x;
  int vid = (bid & 7) * ((int)gridDim.x >> 3) + (bid >> 3);
  tile = vid % 7;
  bh = vid / 7;
}

__global__ __launch_bounds__(256) void k_attn0(const signed char* __restrict__ qkv8,
                                               int* __restrict__ gmInt, u32* __restrict__ sc,
                                               int slotQ, int slotSc) {
  __shared__ __align__(16) signed char Qs[64 * 80];
  __shared__ __align__(16) signed char Ks[128 * 80];
  __shared__ float red[4];
  const int tid = threadIdx.x;
  int tile, bh;
  attn_swz(tile, bh);
  const int r0 = tile * 64;
  const int b = bh / 3, hh = bh % 3;
  const signed char* qb = qkv8 + (long)b * 400 * 576 + hh * 64;
  const signed char* kb = qb + 192;
  const float sQ = read_max16(sc, slotQ) / 127.0f + 1e-8f;
  const float sK = read_max16(sc, slotQ + 1) / 127.0f + 1e-8f;
  const float sSc = sQ * sK * 0.125f;

  {
    int row = tid >> 2, c = tid & 3;
    int4 v = make_int4(0, 0, 0, 0);
    if (r0 + row < 400) v = *(const int4*)(qb + (long)(r0 + row) * 576 + c * 16);
    *(int4*)&Qs[row * 80 + c * 16] = v;
  }
  const int lane = tid & 63, w = tid >> 6, fr = lane & 15, fk = lane >> 4;
  __syncthreads();
  int4v qf = *(const int4v*)&Qs[(16 * w + fr) * 80 + fk * 16];

  int aim = 0;
  int rim = -(1 << 30);
  for (int c0 = 0; c0 < 400; c0 += 128) {
    __syncthreads();
    {
      int trow = tid >> 1, half = tid & 1;
      int4 v0 = make_int4(0, 0, 0, 0), v1 = v0;
      if (c0 + trow < 400) {
        const signed char* kr = kb + (long)(c0 + trow) * 576 + half * 32;
        v0 = *(const int4*)kr;
        v1 = *(const int4*)(kr + 16);
      }
      *(int4*)&Ks[trow * 80 + half * 32] = v0;
      *(int4*)&Ks[trow * 80 + half * 32 + 16] = v1;
    }
    __syncthreads();
#pragma unroll
    for (int tf = 0; tf < 8; ++tf) {
      int4v kf = *(const int4v*)&Ks[(tf * 16 + fr) * 80 + fk * 16];
      int4v s = MFMA_I8(kf, qf, ((int4v){0, 0, 0, 0}));
      const bool tv = (c0 + tf * 16 + fk * 4) < 400;
#pragma unroll
      for (int r = 0; r < 4; ++r) {
        int sv = s[r];
        aim = max(aim, max(sv, -sv));
        if (tv) rim = max(rim, sv);
      }
    }
  }
  rim = max(rim, __shfl_xor(rim, 16));
  rim = max(rim, __shfl_xor(rim, 32));
  const int qloc = 16 * w + fr;
  const int gq = r0 + qloc;
  if (fk == 0 && gq < 400) gmInt[(long)bh * 400 + gq] = rim;
  float m = warpMax((float)aim * sSc);
  if (lane == 0) red[w] = m;
  __syncthreads();
  if (tid == 0) {
    float r = fmaxf(fmaxf(red[0], red[1]), fmaxf(red[2], red[3]));
    atomicMax(sc + slotSc * 16 + (blockIdx.x & 15), __float_as_uint(r));
  }
}

__global__ __launch_bounds__(256) void k_attn1(const signed char* __restrict__ qkv8,
                                               float* __restrict__ gm, float* __restrict__ gl,
                                               const int* __restrict__ gmInt,
                                               u32* __restrict__ sc, int slotQ, int slotSc,
                                               int slotPr) {
  __shared__ __align__(16) signed char Qs[64 * 80];
  __shared__ __align__(16) signed char Ks[128 * 80];
  __shared__ float red[4];
  const int tid = threadIdx.x;
  int tile, bh;
  attn_swz(tile, bh);
  const int r0 = tile * 64;
  const int b = bh / 3, hh = bh % 3;
  const signed char* qb = qkv8 + (long)b * 400 * 576 + hh * 64;
  const signed char* kb = qb + 192;
  const float sQ = read_max16(sc, slotQ) / 127.0f + 1e-8f;
  const float sK = read_max16(sc, slotQ + 1) / 127.0f + 1e-8f;
  const float sSc = sQ * sK * 0.125f;
  const float sS = read_max16(sc, slotSc) / 127.0f + 1e-8f;
  const float c1 = sSc / sS;
  const float c2 = sS * LOG2E;

  {
    int row = tid >> 2, c = tid & 3;
    int4 v = make_int4(0, 0, 0, 0);
    if (r0 + row < 400) v = *(const int4*)(qb + (long)(r0 + row) * 576 + c * 16);
    *(int4*)&Qs[row * 80 + c * 16] = v;
  }
  const int lane = tid & 63, w = tid >> 6, fr = lane & 15, fk = lane >> 4;
  __syncthreads();
  int4v qf = *(const int4v*)&Qs[(16 * w + fr) * 80 + fk * 16];

  const int qloc = 16 * w + fr;
  const int gq = r0 + qloc;
  const int gqc = (gq > 399) ? 399 : gq;
  const int mint = gmInt[(long)bh * 400 + gqc];
  const float cm = fminf(fmaxf(rintf((float)mint * c1), -128.f), 127.f);

  float sum = 0.f;
  for (int c0 = 0; c0 < 400; c0 += 128) {
    __syncthreads();
    {
      int trow = tid >> 1, half = tid & 1;
      int4 v0 = make_int4(0, 0, 0, 0), v1 = v0;
      if (c0 + trow < 400) {
        const signed char* kr = kb + (long)(c0 + trow) * 576 + half * 32;
        v0 = *(const int4*)kr;
        v1 = *(const int4*)(kr + 16);
      }
      *(int4*)&Ks[trow * 80 + half * 32] = v0;
      *(int4*)&Ks[trow * 80 + half * 32 + 16] = v1;
    }
    __syncthreads();
#pragma unroll
    for (int tf = 0; tf < 8; ++tf) {
      int4v kf = *(const int4v*)&Ks[(tf * 16 + fr) * 80 + fk * 16];
      int4v s = MFMA_I8(kf, qf, ((int4v){0, 0, 0, 0}));
      if ((c0 + tf * 16 + fk * 4) < 400) {
#pragma unroll
        for (int r = 0; r < 4; ++r) {
          float cf = fminf(fmaxf(rintf((float)s[r] * c1), -128.f), 127.f);
          sum += exp2f((cf - cm) * c2);
        }
      }
    }
  }
  sum += __shfl_xor(sum, 16);
  sum += __shfl_xor(sum, 32);
  float cand = 0.f;
  if (fk == 0 && gq < 400) {
    gm[(long)bh * 400 + gq] = cm;
    gl[(long)bh * 400 + gq] = sum;
    cand = 1.0f / sum;
  }
  float m = warpMax(cand);
  if (lane == 0) red[w] = m;
  __syncthreads();
  if (tid == 0) {
    float r = fmaxf(fmaxf(red[0], red[1]), fmaxf(red[2], red[3]));
    atomicMax(sc + slotPr * 16 + (blockIdx.x & 15), __float_as_uint(r));
  }
}

__global__ __launch_bounds__(256) void k_attn_pv(
    const signed char* __restrict__ qkv8, const signed char* __restrict__ vt8,
    const int* __restrict__ colsumV, float* __restrict__ ctx, const float* __restrict__ gm,
    const float* __restrict__ gl, u32* __restrict__ sc, int slotQ, int slotSc, int slotPr,
    int slotCtx) {
  __shared__ __align__(16) signed char Qs[64 * 80];
  __shared__ __align__(16) signed char Ks[128 * 80];
  __shared__ __align__(16) signed char Vs[64 * 144];
  __shared__ __align__(16) signed char Ps[64 * 144];
  __shared__ int colsV[64];
  __shared__ float red[4];
  const int tid = threadIdx.x;
  int tile, bh;
  attn_swz(tile, bh);
  const int r0 = tile * 64;
  const int b = bh / 3, hh = bh % 3;
  const signed char* qb = qkv8 + (long)b * 400 * 576 + hh * 64;
  const signed char* kb = qb + 192;
  const signed char* vtb = vt8 + (long)bh * 25600;
  const float sQ = read_max16(sc, slotQ) / 127.0f + 1e-8f;
  const float sK = read_max16(sc, slotQ + 1) / 127.0f + 1e-8f;
  const float sV = read_max16(sc, slotQ + 2) / 127.0f + 1e-8f;
  const float sSc = sQ * sK * 0.125f;
  const float sS = read_max16(sc, slotSc) / 127.0f + 1e-8f;
  const float sP = read_max16(sc, slotPr) / 255.0f + 1e-8f;
  const float sPV = sP * sV;
  const float c1 = sSc / sS;
  const float c2 = sS * LOG2E;

  {
    int row = tid >> 2, c = tid & 3;
    int4 v = make_int4(0, 0, 0, 0);
    if (r0 + row < 400) v = *(const int4*)(qb + (long)(r0 + row) * 576 + c * 16);
    *(int4*)&Qs[row * 80 + c * 16] = v;
  }
  if (tid < 64) colsV[tid] = colsumV[bh * 64 + tid];
  const int lane = tid & 63, w = tid >> 6, fr = lane & 15, fk = lane >> 4;
  __syncthreads();
  int4v qf = *(const int4v*)&Qs[(16 * w + fr) * 80 + fk * 16];

  const int qloc = 16 * w + fr;
  int gq = r0 + qloc;
  if (gq > 399) gq = 399;
  const float cm = gm[(long)bh * 400 + gq];
  const float invLsp = 1.0f / (gl[(long)bh * 400 + gq] * sP);

  int4v accd[4];
#pragma unroll
  for (int dt = 0; dt < 4; ++dt) accd[dt] = (int4v){0, 0, 0, 0};

  for (int c0 = 0; c0 < 400; c0 += 128) {
    __syncthreads();
    {  // K chunk
      int trow = tid >> 1, half = tid & 1;
      int4 v0 = make_int4(0, 0, 0, 0), v1 = v0;
      if (c0 + trow < 400) {
        const signed char* kr = kb + (long)(c0 + trow) * 576 + half * 32;
        v0 = *(const int4*)kr;
        v1 = *(const int4*)(kr + 16);
      }
      *(int4*)&Ks[trow * 80 + half * 32] = v0;
      *(int4*)&Ks[trow * 80 + half * 32 + 16] = v1;
    }
    {  // V^T chunk
      int d = tid >> 2, seg = tid & 3;
      int t0 = c0 + seg * 32;
      int4 u0 = make_int4(0, 0, 0, 0), u1 = u0;
      if (t0 < 400) u0 = *(const int4*)(vtb + d * 400 + t0);
      if (t0 + 16 < 400) u1 = *(const int4*)(vtb + d * 400 + t0 + 16);
      *(int4*)&Vs[d * 144 + seg * 32] = u0;
      *(int4*)&Vs[d * 144 + seg * 32 + 16] = u1;
    }
    __syncthreads();
#pragma unroll
    for (int tf = 0; tf < 8; ++tf) {
      int4v kf = *(const int4v*)&Ks[(tf * 16 + fr) * 80 + fk * 16];
      int4v s = MFMA_I8(kf, qf, ((int4v){0, 0, 0, 0}));
      const int tbase = c0 + tf * 16 + fk * 4;
      u32 pack = 0;
      if (tbase < 400) {
#pragma unroll
        for (int r = 0; r < 4; ++r) {
          float cf = fminf(fmaxf(rintf((float)s[r] * c1), -128.f), 127.f);
          float e = exp2f((cf - cm) * c2);
          float pu = fminf(fmaxf(rintf(e * invLsp), 0.f), 255.f);
          int pc = (int)pu - 128;
          pack |= ((u32)(pc & 0xff)) << (8 * r);
        }
      }
      *(u32*)&Ps[qloc * 144 + tf * 16 + fk * 4] = pack;
    }
    __syncthreads();
    int4v pf0 = *(const int4v*)&Ps[qloc * 144 + fk * 16];
    int4v pf1 = *(const int4v*)&Ps[qloc * 144 + 64 + fk * 16];
#pragma unroll
    for (int dt = 0; dt < 4; ++dt) {
      int4v vf0 = *(const int4v*)&Vs[(dt * 16 + fr) * 144 + fk * 16];
      int4v vf1 = *(const int4v*)&Vs[(dt * 16 + fr) * 144 + 64 + fk * 16];
      accd[dt] = MFMA_I8(vf0, pf0, accd[dt]);
      accd[dt] = MFMA_I8(vf1, pf1, accd[dt]);
    }
  }
  float vmax = 0.f;
  const int q = r0 + qloc;
  if (q < 400) {
#pragma unroll
    for (int dt = 0; dt < 4; ++dt) {
      const int d0 = dt * 16 + fk * 4;
      float4 o;
      o.x = sPV * (float)(accd[dt][0] + 128 * colsV[d0 + 0]);
      o.y = sPV * (float)(accd[dt][1] + 128 * colsV[d0 + 1]);
      o.z = sPV * (float)(accd[dt][2] + 128 * colsV[d0 + 2]);
      o.w = sPV * (float)(accd[dt][3] + 128 * colsV[d0 + 3]);
      vmax = fmaxf(vmax, fmaxf(fmaxf(fabsf(o.x), fabsf(o.y)), fmaxf(fabsf(o.z), fabsf(o.w))));
      *(float4*)&ctx[(long)(b * 400 + q) * 192 + hh * 64 + d0] = o;
    }
  }
  float m = warpMax(vmax);
  if (lane == 0) red[w] = m;
  __syncthreads();
  if (tid == 0) {
    float r = fmaxf(fmaxf(red[0], red[1]), fmaxf(red[2], red[3]));
    atomicMax(sc + slotCtx * 16 + (blockIdx.x & 15), __float_as_uint(r));
  }
}

// ---------------------------------------------------------------------------
// final pool + logits
// ---------------------------------------------------------------------------
__global__ __launch_bounds__(192) void k_pool(const float* __restrict__ xln,
                                              float* __restrict__ pooled,
                                              u32* __restrict__ slot) {
  int b = blockIdx.x, d = threadIdx.x;
  float sum = 0.f;
  for (int s = 0; s < 400; ++s) sum += xln[((long)b * 400 + s) * 192 + d];
  float v = sum / 400.0f;
  pooled[(long)b * 192 + d] = v;
  __shared__ float red[3];
  float m = warpMax(fabsf(v));
  if ((d & 63) == 0) red[d >> 6] = m;
  __syncthreads();
  if (d == 0)
    atomicMax(slot + (b & 15), __float_as_uint(fmaxf(fmaxf(red[0], red[1]), red[2])));
}

__global__ __launch_bounds__(64) void k_logits(const float* __restrict__ pooled,
                                               const float* __restrict__ clfq,
                                               const float* __restrict__ clfb,
                                               const u32* __restrict__ sc,
                                               float* __restrict__ out) {
  int c = blockIdx.x, b = blockIdx.y, lane = threadIdx.x;
  float sp = read_max16(sc, SLOT_POOL) / 127.0f + 1e-8f;
  float acc = 0.f;
#pragma unroll
  for (int j = 0; j < 3; ++j) {
    int d = lane + 64 * j;
    acc += fqs(pooled[(long)b * 192 + d], sp) * clfq[c * 192 + d];
  }
#pragma unroll
  for (int o = 32; o > 0; o >>= 1) acc += __shfl_down(acc, o);
  if (lane == 0) out[b * 7 + c] = acc + clfb[c];
}

// ---------------------------------------------------------------------------
// host
// ---------------------------------------------------------------------------
static inline int gsz(long n4, long cap) {
  long g = (n4 + 255) / 256;
  return (int)(g < cap ? g : cap);
}

extern "C" void kernel_launch(void* const* d_in, const int* in_sizes, int n_in,
                              void* d_out, int out_size, void* d_ws, size_t ws_size,
                              hipStream_t stream) {
  (void)in_sizes; (void)n_in; (void)out_size; (void)ws_size;

  const float* x = (const float*)d_in[0];
  const float* pw = (const float*)d_in[1];
  const float* pb = (const float*)d_in[2];
  const float* ln1g = (const float*)d_in[3];
  const float* ln1b = (const float*)d_in[4];
  const float* wqkv = (const float*)d_in[5];
  const float* bqkv = (const float*)d_in[6];
  const float* wo = (const float*)d_in[7];
  const float* bo = (const float*)d_in[8];
  const float* ln2g = (const float*)d_in[9];
  const float* ln2b = (const float*)d_in[10];
  const float* w1 = (const float*)d_in[11];
  const float* b1 = (const float*)d_in[12];
  const float* w2 = (const float*)d_in[13];
  const float* b2 = (const float*)d_in[14];
  const float* lnfg = (const float*)d_in[15];
  const float* lnfb = (const float*)d_in[16];
  const float* clfw = (const float*)d_in[17];
  const float* clfb = (const float*)d_in[18];

  float* ws = (float*)d_ws;
  u32* sc = (u32*)d_ws;
  float* GM = ws + OFF_GM;
  int* GMI = (int*)GM;
  float* GL = ws + OFF_GL;
  float* POOL = ws + OFF_POOL;
  float* PWQ = ws + OFF_PWQ;
  float* CLFQ = ws + OFF_CLFQ;
  float* H = ws + OFF_H;
  float* Af = ws + OFF_A;
  // A region: i8 hi plane (19.66MB) + i8 lo plane (19.66MB) + row scales (0.41MB)
  signed char* AH8 = (signed char*)(ws + OFF_A);
  signed char* AL8 = AH8 + 19660800;
  float* SAROW = (float*)(AH8 + 2 * 19660800);
  signed char* U8 = (signed char*)(ws + OFF_U);
  signed char* VT8 = U8 + 58982400;
  int* COLSUM = (int*)POOL;
  signed char* WQC = (signed char*)POOL;
  signed char* WOC2 = (signed char*)POOL;          // 36,864 B (wo)
  signed char* W1C2 = (signed char*)POOL + 36864;  // 147,456 B (w1; w2 reuses)
  signed char* W2C2 = (signed char*)POOL + 36864;
  float* out = (float*)d_out;

  k_zero<<<(N_SLOT_WORDS + 255) / 256, 256, 0, stream>>>(sc, N_SLOT_WORDS);

  auto amax = [&](const float* p, long n, int slot) {
    k_absmax<<<gsz(n / 4, 256), 256, 0, stream>>>((const float4*)p, n / 4, sc + slot * 16);
  };
  amax(pw, 3840, SLOT_PW);
  amax(clfw, 1344, SLOT_CLF);
  amax(x, 2048000, SLOT_X);
  for (int i = 0; i < NL; ++i) {
    int Lb = 16 + i * 16;
    amax(wqkv + (long)i * 110592, 110592, Lb + 0);
    amax(wo + (long)i * 36864, 36864, Lb + 1);
    amax(w1 + (long)i * 147456, 147456, Lb + 2);
    amax(w2 + (long)i * 147456, 147456, Lb + 3);
  }
  k_quant4<<<gsz(960, 256), 256, 0, stream>>>((const float4*)pw, (float4*)PWQ, 960, sc, SLOT_PW);
  k_quant4<<<gsz(336, 256), 256, 0, stream>>>((const float4*)clfw, (float4*)CLFQ, 336, sc,
                                              SLOT_CLF);

  // patch embed -> Af -> quant into H; first LN -> i16 planes
  k_patch<<<12800, 192, 0, stream>>>(x, PWQ, pb, sc, Af, sc + SLOT_EMB * 16);
  k_quant4<<<2048, 256, 0, stream>>>((const float4*)Af, (float4*)H, 19660800 / 4, sc, SLOT_EMB);
  k_ln<true><<<(int)(ROWS / 4), 256, 0, stream>>>(H, ln1g, ln1b, AH8, AL8, SAROW, nullptr,
                                                  (int)ROWS);

  for (int i = 0; i < NL; ++i) {
    int Lb = 16 + i * 16;
    // --- attention ---
    k_wquant<<<108, 256, 0, stream>>>((const float4*)(wqkv + (long)i * 110592), (u32*)WQC,
                                      27648, sc, Lb + 0);
    k_gemm16<false, 1><<<4800, 256, 0, stream>>>(AH8, AL8, SAROW, WQC, Lb + 0, bqkv + i * 576,
                                                 nullptr, 576, 6, sc, Lb + 4, 192);
    k_gemm16<false, 2><<<4800, 256, 0, stream>>>(AH8, AL8, SAROW, WQC, Lb + 0, bqkv + i * 576,
                                                 U8, 576, 6, sc, Lb + 4, 192);
    k_vt<<<768, 256, 0, stream>>>(U8, VT8, COLSUM);
    k_attn0<<<5376, 256, 0, stream>>>(U8, GMI, sc, Lb + 4, Lb + 7);
    k_attn1<<<5376, 256, 0, stream>>>(U8, GM, GL, GMI, sc, Lb + 4, Lb + 7, Lb + 8);
    k_attn_pv<<<5376, 256, 0, stream>>>(U8, VT8, COLSUM, Af, GM, GL, sc, Lb + 4, Lb + 7,
                                        Lb + 8, Lb + 9);
    // ctx fp32 (Af) -> int8 codes (U8 head); wo codes into POOL
    k_quant_codes<<<2048, 256, 0, stream>>>((const float4*)Af, (u32*)U8, 19660800 / 4, sc,
                                            Lb + 9);
    k_wquant<<<36, 256, 0, stream>>>((const float4*)(wo + (long)i * 36864), (u32*)WOC2, 9216,
                                     sc, Lb + 1);
    {
      dim3 g(1, 800);
      k_gemm8<1><<<g, 256, 0, stream>>>(U8, Lb + 9, WOC2, Lb + 1, bo + i * 192, nullptr, 192,
                                        192, sc, Lb + 10);
      k_gemm8<3><<<g, 256, 0, stream>>>(U8, Lb + 9, WOC2, Lb + 1, bo + i * 192, H, 192, 192,
                                        sc, Lb + 10);
    }
    // LN2 -> i16 planes
    k_ln<true><<<(int)(ROWS / 4), 256, 0, stream>>>(H, ln2g + i * 192, ln2b + i * 192, AH8,
                                                    AL8, SAROW, nullptr, (int)ROWS);
    // --- MLP ---
    k_wquant<<<144, 256, 0, stream>>>((const float4*)(w1 + (long)i * 147456), (u32*)W1C2,
                                      36864, sc, Lb + 2);
    k_gemm16<true, 1><<<6400, 256, 0, stream>>>(AH8, AL8, SAROW, W1C2, Lb + 2, b1 + i * 768,
                                                nullptr, 768, 8, sc, Lb + 11, 768);
    k_gemm16<true, 2><<<6400, 256, 0, stream>>>(AH8, AL8, SAROW, W1C2, Lb + 2, b1 + i * 768,
                                                U8, 768, 8, sc, Lb + 11, 768);
    k_wquant<<<144, 256, 0, stream>>>((const float4*)(w2 + (long)i * 147456), (u32*)W2C2,
                                      36864, sc, Lb + 3);
    {
      dim3 g(1, 800);
      k_gemm8<1><<<g, 256, 0, stream>>>(U8, Lb + 11, W2C2, Lb + 3, b2 + i * 192, nullptr, 192,
                                        768, sc, Lb + 12);
      k_gemm8<3><<<g, 256, 0, stream>>>(U8, Lb + 11, W2C2, Lb + 3, b2 + i * 192, H, 192, 768,
                                        sc, Lb + 12);
    }
    if (i < NL - 1) {
      k_ln<true><<<(int)(ROWS / 4), 256, 0, stream>>>(H, ln1g + (i + 1) * 192,
                                                      ln1b + (i + 1) * 192, AH8, AL8, SAROW,
                                                      nullptr, (int)ROWS);
    } else {
      k_ln<false><<<(int)(ROWS / 4), 256, 0, stream>>>(H, lnfg, lnfb, nullptr, nullptr,
                                                       nullptr, Af, (int)ROWS);
    }
  }

  // pool + classifier (POOL region free again: weight codes dead)
  k_pool<<<256, 192, 0, stream>>>(Af, POOL, sc + SLOT_POOL * 16);
  {
    dim3 g(7, 256);
    k_logits<<<g, 64, 0, stream>>>(POOL, CLFQ, clfb, sc, out);
  }
}